// Round 5
// baseline (521.030 us; speedup 1.0000x reference)
//
#include <hip/hip_runtime.h>
#include <cmath>

#define BB 4
#define NN 4096
#define CC 1024
#define HH 8
#define DD 128
#define MM (BB*NN)   // 16384
#define NP (NN+2)    // padded rows per batch

typedef __attribute__((ext_vector_type(8))) short bf16x8;
typedef __attribute__((ext_vector_type(4))) float f32x4;

static __device__ __forceinline__ unsigned short f2bf(float f) {
    unsigned int u = __float_as_uint(f);
    unsigned int r = (u + 0x7FFF + ((u >> 16) & 1)) >> 16;
    return (unsigned short)r;
}
static __device__ __forceinline__ float bf2f(short s) {
    return __uint_as_float(((unsigned int)(unsigned short)s) << 16);
}
static __device__ __forceinline__ float4 bf4(ushort4 u) {
    float4 f;
    f.x = __uint_as_float((unsigned int)u.x << 16);
    f.y = __uint_as_float((unsigned int)u.y << 16);
    f.z = __uint_as_float((unsigned int)u.z << 16);
    f.w = __uint_as_float((unsigned int)u.w << 16);
    return f;
}

static __device__ __forceinline__ void load_lds16(const void* g, void* l) {
    __builtin_amdgcn_global_load_lds(
        (const __attribute__((address_space(1))) unsigned int*)g,
        (__attribute__((address_space(3))) unsigned int*)l, 16, 0, 0);
}

// XOR bank swizzle for [*][64]-short tiles (128B rows, 8 x 16B slots/row).
static __device__ __forceinline__ int swz(int row, int ko) {
    return (row * 64 + ko) ^ ((row & 7) << 3);
}

#define CFENCE() asm volatile("" ::: "memory")
#define BAR() do { CFENCE(); __builtin_amdgcn_s_barrier(); CFENCE(); } while (0)

// ---------------------------------------------------------------------------
// P1: xpad[b][p][c] (bf16), p in [0,NP): rows 0 and NP-1 zero, p = x[b][p-1]
// ---------------------------------------------------------------------------
__global__ __launch_bounds__(256) void padx_kernel(
    const float* __restrict__ x, unsigned short* __restrict__ xpad)
{
    const int r = blockIdx.x;
    const int b = r / NP, p = r % NP;
    const int c = threadIdx.x * 4;
    ushort4 v = {0, 0, 0, 0};
    if (p >= 1 && p <= NN) {
        const float4 f = *(const float4*)&x[(size_t)(b * NN + p - 1) * CC + c];
        v.x = f2bf(f.x); v.y = f2bf(f.y); v.z = f2bf(f.z); v.w = f2bf(f.w);
    }
    *(ushort4*)&xpad[(size_t)r * CC + c] = v;
}

// ---------------------------------------------------------------------------
// P2: dst[c][r] = bf16(src[r][c])
// ---------------------------------------------------------------------------
__global__ __launch_bounds__(256) void transpose_bf16_kernel(
    const float* __restrict__ src, unsigned short* __restrict__ dst,
    int R, int Cc)
{
    __shared__ float t[32][33];
    const int r0 = blockIdx.y * 32, c0 = blockIdx.x * 32;
    const int tx = threadIdx.x & 31, ty = threadIdx.x >> 5;
    #pragma unroll
    for (int i = 0; i < 4; ++i) {
        int r = ty + i * 8;
        t[r][tx] = src[(size_t)(r0 + r) * Cc + c0 + tx];
    }
    __syncthreads();
    #pragma unroll
    for (int i = 0; i < 4; ++i) {
        int r = ty + i * 8;
        dst[(size_t)(c0 + r) * R + r0 + tx] = f2bf(t[tx][r]);
    }
}

// ---------------------------------------------------------------------------
// stage_half: one 128x64 bf16 half-tile (16KB), 512 threads x 2 x 16B loads.
// LDS dest linear (global_load_lds constraint); source slot pre-swizzled.
// ---------------------------------------------------------------------------
static __device__ __forceinline__ void stage_half(
    const unsigned short* __restrict__ g, int stride,
    unsigned short* lds, int tid)
{
    const int wb = tid & ~63;
    #pragma unroll
    for (int l = 0; l < 2; ++l) {
        const int c = l * 512 + tid;            // 0..1023
        const int row = c >> 3;                 // 0..127
        const int col8 = (c & 7) ^ (row & 7);   // inverse swizzle on source
        load_lds16(&g[(size_t)row * stride + col8 * 8],
                   &lds[(size_t)(l * 512 + wb) * 8]);
    }
}

// 4 A/B fragments (swizzled reads) from a half-tile base.
static __device__ __forceinline__ void lda4(
    const unsigned short* __restrict__ h, int lr0, int rl, int ko, bf16x8* o)
{
    #pragma unroll
    for (int i = 0; i < 4; ++i)
        o[i] = *(const bf16x8*)&h[swz(lr0 + i * 16 + rl, ko)];
}

// 16 MFMAs: one quadrant (4 mf x 4 nf), setprio-wrapped (T5).
static __device__ __forceinline__ void mfma_quad(
    f32x4 (*acc)[4], int mfb, const bf16x8* af, const bf16x8* bfr)
{
    __builtin_amdgcn_s_setprio(1);
    #pragma unroll
    for (int i = 0; i < 4; ++i)
        #pragma unroll
        for (int nf = 0; nf < 4; ++nf)
            acc[mfb + i][nf] = __builtin_amdgcn_mfma_f32_16x16x32_bf16(
                af[i], bfr[nf], acc[mfb + i][nf], 0, 0, 0);
    __builtin_amdgcn_s_setprio(0);
}

// ---------------------------------------------------------------------------
// 4-phase K-tile body (T3+T4): per phase {ds_read frags | stage 1 half-tile ->
// barrier -> 16 MFMA -> barrier}. One counted vmcnt(2) per K-tile at phase 0.
// SA/SB: [buf][half][128*64]. Wave reads A-half wr, B-half wc>>1.
// ---------------------------------------------------------------------------
#define KTILE_4PHASE(Ah, Bh, blr0, STAGE_A0, STAGE_A1, STAGE_B0, STAGE_B1, HAVE_NEXT) \
    do {                                                                     \
        bf16x8 af_[4], af2_[4], bfr_[4], bfr2_[4];                           \
        /* phase 0 */                                                        \
        if (HAVE_NEXT) {                                                     \
            STAGE_A0;                                                        \
            asm volatile("s_waitcnt vmcnt(2)" ::: "memory");                 \
        } else {                                                             \
            asm volatile("s_waitcnt vmcnt(0)" ::: "memory");                 \
        }                                                                    \
        BAR();                                                               \
        lda4(Ah, 0, rl, ko0, af_);                                           \
        lda4(Bh, blr0, rl, ko0, bfr_);                                       \
        mfma_quad(acc, 0, af_, bfr_);                                        \
        BAR();                                                               \
        /* phase 1 */                                                        \
        lda4(Ah, 64, rl, ko0, af2_);                                         \
        if (HAVE_NEXT) { STAGE_A1; }                                         \
        BAR();                                                               \
        mfma_quad(acc, 4, af2_, bfr_);                                       \
        BAR();                                                               \
        /* phase 2 */                                                        \
        lda4(Ah, 0, rl, ko1, af_);                                           \
        lda4(Bh, blr0, rl, ko1, bfr2_);                                      \
        if (HAVE_NEXT) { STAGE_B0; }                                         \
        BAR();                                                               \
        mfma_quad(acc, 0, af_, bfr2_);                                       \
        BAR();                                                               \
        /* phase 3 */                                                        \
        lda4(Ah, 64, rl, ko1, af2_);                                         \
        if (HAVE_NEXT) { STAGE_B1; }                                         \
        BAR();                                                               \
        mfma_quad(acc, 4, af2_, bfr2_);                                      \
        BAR();                                                               \
    } while (0)

// ---------------------------------------------------------------------------
// K1: qk = x @ qk_w + qk_b ; elu+1 ; q,k stored bf16; k column sums -> ksum
// 256x256 tile, BK=64, 8 waves (2Mx4N), 4-phase pipelined K-loop.
// ---------------------------------------------------------------------------
__global__ __launch_bounds__(512) void gemm_qk_mfma(
    const unsigned short* __restrict__ xpad, const unsigned short* __restrict__ wT,
    const float* __restrict__ bias, unsigned short* __restrict__ qbuf,
    unsigned short* __restrict__ kbuf, float* __restrict__ ksum)
{
    __shared__ __align__(16) unsigned short SA[2][2][8192];
    __shared__ __align__(16) unsigned short SB[2][2][8192];
    const int m0 = blockIdx.x * 256;
    const int n0 = blockIdx.y * 256;
    const int tid = threadIdx.x;
    const int lane = tid & 63;
    const int wv = tid >> 6;
    const int wr = wv >> 2, wc = wv & 3;
    const int b = m0 >> 12;
    const int rbase = m0 + 1 + 2 * b;
    const int rl = lane & 15;
    const int ko0 = (lane >> 4) * 8;
    const int ko1 = 32 + ko0;
    const int blr0 = (wc & 1) * 64;

    const unsigned short* Agl = &xpad[(size_t)rbase * CC];
    const unsigned short* Bgl = &wT[(size_t)n0 * CC];

    f32x4 acc[8][4] = {};
    // prologue: stage K-tile 0 (4 half-tiles, 8 loads/thread)
    stage_half(Agl, CC, SA[0][0], tid);
    stage_half(&Agl[(size_t)128 * CC], CC, SA[0][1], tid);
    stage_half(Bgl, CC, SB[0][0], tid);
    stage_half(&Bgl[(size_t)128 * CC], CC, SB[0][1], tid);

    const int NT = 16;
    for (int t = 0; t < NT; ++t) {
        const int cur = t & 1;
        const unsigned short* Ah = SA[cur][wr];
        const unsigned short* Bh = SB[cur][wc >> 1];
        const int k1 = (t + 1) * 64;
        KTILE_4PHASE(Ah, Bh, blr0,
            stage_half(&Agl[k1], CC, SA[cur ^ 1][0], tid),
            stage_half(&Agl[(size_t)128 * CC + k1], CC, SA[cur ^ 1][1], tid),
            stage_half(&Bgl[k1], CC, SB[cur ^ 1][0], tid),
            stage_half(&Bgl[(size_t)128 * CC + k1], CC, SB[cur ^ 1][1], tid),
            (t + 1 < NT));
    }

    const bool khalf = (n0 >= CC);
    const int col = lane & 15, rb4 = (lane >> 4) * 4;
    #pragma unroll
    for (int nf = 0; nf < 4; ++nf) {
        const int n = n0 + wc * 64 + nf * 16 + col;
        const float bn = bias[n];
        float csum = 0.0f;
        #pragma unroll
        for (int mf = 0; mf < 8; ++mf)
            #pragma unroll
            for (int r = 0; r < 4; ++r) {
                const int m = m0 + wr * 128 + mf * 16 + rb4 + r;
                float v = acc[mf][nf][r] + bn;
                v = (v > 0.0f) ? (v + 1.0f) : __expf(v);   // elu(v)+1
                csum += v;
                if (!khalf) qbuf[(size_t)m * CC + n] = f2bf(v);
                else        kbuf[(size_t)m * CC + (n - CC)] = f2bf(v);
            }
        if (khalf) atomicAdd(&ksum[b * CC + (n - CC)], csum);
    }
}

// ---------------------------------------------------------------------------
// K3: thread = (row, head). z[m,h] = 1/(dot(q_head, ksum_head)/N + 1e-6);
// RoPE q in place (barrier-ordered); kr -> krP[b][h][n][d] bf16.
// ---------------------------------------------------------------------------
__global__ __launch_bounds__(256) void rope_z_kernel(
    unsigned short* __restrict__ qbuf, const unsigned short* __restrict__ kbuf,
    const float* __restrict__ ksum, unsigned short* __restrict__ krP,
    float* __restrict__ zbuf)
{
    const int tid = threadIdx.x;
    const int row = tid >> 3;            // 0..31
    const int h = tid & 7;
    const int m = blockIdx.x * 32 + row;
    const int b = m >> 12;
    const int pos = m & (NN - 1);
    unsigned short* qrow = qbuf + (size_t)m * CC + h * DD;
    const unsigned short* krow = kbuf + (size_t)m * CC + h * DD;

    bf16x8 qv[16], kv8[16];
    #pragma unroll
    for (int i = 0; i < 16; ++i) {
        qv[i]  = *(const bf16x8*)&qrow[i * 8];
        kv8[i] = *(const bf16x8*)&krow[i * 8];
    }
    const float* km = ksum + b * CC + h * DD;
    float dot = 0.0f;
    #pragma unroll
    for (int i = 0; i < 16; ++i)
        #pragma unroll
        for (int jq = 0; jq < 8; ++jq)
            dot = fmaf(bf2f(qv[i][jq]), km[i * 8 + jq], dot);
    dot *= (1.0f / (float)NN);
    __syncthreads();   // all q reads complete before in-place writes
    zbuf[(size_t)m * HH + h] = 1.0f / (dot + 1e-6f);

    #pragma unroll
    for (int c8 = 0; c8 < 8; ++c8) {
        bf16x8 qpr, qpi, kpr, kpi;
        #pragma unroll
        for (int u = 0; u < 8; ++u) {
            const int jj = c8 * 8 + u;
            const int j = h * 64 + jj;
            const float theta = __builtin_exp2f((float)j * (-13.287712379549449f / 512.0f));
            float sv, cv;
            __sincosf((float)pos * theta, &sv, &cv);
            const int li = c8 * 2 + (u >> 2);
            const int le = (2 * u) & 7;
            const float q0 = bf2f(qv[li][le]),  q1 = bf2f(qv[li][le + 1]);
            const float k0 = bf2f(kv8[li][le]), k1 = bf2f(kv8[li][le + 1]);
            qpr[u] = (short)f2bf(cv * q0 - sv * q1);
            qpi[u] = (short)f2bf(cv * q1 + sv * q0);
            kpr[u] = (short)f2bf(cv * k0 - sv * k1);
            kpi[u] = (short)f2bf(cv * k1 + sv * k0);
        }
        *(bf16x8*)&qbuf[(size_t)m * CC + h * 64 + c8 * 8] = qpr;
        *(bf16x8*)&qbuf[(size_t)m * CC + 512 + h * 64 + c8 * 8] = qpi;
        unsigned short* kp1 = &krP[((size_t)(b * 8 + (h >> 1)) * NN + pos) * DD + (h & 1) * 64 + c8 * 8];
        unsigned short* kp2 = &krP[((size_t)(b * 8 + 4 + (h >> 1)) * NN + pos) * DD + (h & 1) * 64 + c8 * 8];
        *(bf16x8*)kp1 = kpr;
        *(bf16x8*)kp2 = kpi;
    }
}

// ---------------------------------------------------------------------------
// K4: kvpart[slice][bh][d][e] = sum over slice's 256 n of kr[n,d]*v[n,e]
// ---------------------------------------------------------------------------
__global__ __launch_bounds__(256) void kv_kernel(
    const unsigned short* __restrict__ krP, const unsigned short* __restrict__ xpad,
    float* __restrict__ kvpart)
{
    __shared__ float ksm[8][132];
    __shared__ float vsm[8][132];
    const int bh = blockIdx.x;
    const int slice = blockIdx.y;
    const int b = bh >> 3, h = bh & 7;
    const int n0 = slice * 256;
    const int tid = threadIdx.x;
    const int td = (tid >> 4) * 8;
    const int te = (tid & 15) * 8;
    const unsigned short* kp = krP + ((size_t)bh * NN + n0) * DD;
    const unsigned short* vp = xpad + ((size_t)(b * NP) + 1 + n0) * CC + h * DD;
    const int sr = tid >> 5;
    const int sc = (tid & 31) * 4;
    float acc[8][8] = {};
    ushort4 kq = *(const ushort4*)&kp[(size_t)sr * DD + sc];
    ushort4 vq = *(const ushort4*)&vp[(size_t)sr * CC + sc];
    for (int r0 = 0; r0 < 256; r0 += 8) {
        *(float4*)&ksm[sr][sc] = bf4(kq);
        *(float4*)&vsm[sr][sc] = bf4(vq);
        __syncthreads();
        if (r0 + 8 < 256) {
            kq = *(const ushort4*)&kp[(size_t)(r0 + 8 + sr) * DD + sc];
            vq = *(const ushort4*)&vp[(size_t)(r0 + 8 + sr) * CC + sc];
        }
        #pragma unroll
        for (int r = 0; r < 8; ++r) {
            float a[8], bv[8];
            *(float4*)&a[0]  = *(const float4*)&ksm[r][td];
            *(float4*)&a[4]  = *(const float4*)&ksm[r][td + 4];
            *(float4*)&bv[0] = *(const float4*)&vsm[r][te];
            *(float4*)&bv[4] = *(const float4*)&vsm[r][te + 4];
            #pragma unroll
            for (int i = 0; i < 8; ++i)
                #pragma unroll
                for (int j = 0; j < 8; ++j)
                    acc[i][j] = fmaf(a[i], bv[j], acc[i][j]);
        }
        __syncthreads();
    }
    float* op = kvpart + ((size_t)slice * 32 + bh) * (DD * DD);
    #pragma unroll
    for (int i = 0; i < 8; ++i)
        #pragma unroll
        for (int j = 0; j < 8; j += 4)
            *(float4*)&op[(td + i) * DD + te + j] = *(float4*)&acc[i][j];
}

// ---------------------------------------------------------------------------
// K4b: kvT[bh][e][d] = bf16( (1/64) * sum over 16 slices kvpart[sl][bh][d][e] )
// ---------------------------------------------------------------------------
__global__ __launch_bounds__(256) void kv_reduce_t_kernel(
    const float* __restrict__ kvpart, unsigned short* __restrict__ kvT)
{
    __shared__ float t[32][33];
    const int bh = blockIdx.y;
    const int dblk = blockIdx.x >> 2, eblk = blockIdx.x & 3;
    const int tx = threadIdx.x & 31, ty = threadIdx.x >> 5;
    #pragma unroll
    for (int i = 0; i < 4; ++i) {
        const int d = dblk * 32 + ty + i * 8;
        float s = 0.0f;
        #pragma unroll
        for (int sl = 0; sl < 16; ++sl)
            s += kvpart[((size_t)sl * 32 + bh) * (DD * DD) + (size_t)d * DD + eblk * 32 + tx];
        t[ty + i * 8][tx] = s * (1.0f / 64.0f);
    }
    __syncthreads();
    #pragma unroll
    for (int i = 0; i < 4; ++i) {
        const int e = ty + i * 8;
        kvT[((size_t)bh * DD + eblk * 32 + e) * DD + dblk * 32 + tx] = f2bf(t[tx][e]);
    }
}

// ---------------------------------------------------------------------------
// K6 (fused): out = z * (qr @ kv) + conv1d(x, lepe_w, SAME) + lepe_b
// attn pre-pass (plain 2-phase, 2 tiles), z-scale, then 48-tile conv loop
// with the 4-phase pipelined schedule. Epilogue is a pure store.
// ---------------------------------------------------------------------------
__global__ __launch_bounds__(512) void lepe_mfma(
    const unsigned short* __restrict__ xpad, const unsigned short* __restrict__ wT,
    const float* __restrict__ bias, const unsigned short* __restrict__ qr,
    const unsigned short* __restrict__ kvT, const float* __restrict__ z,
    float* __restrict__ out)
{
    __shared__ __align__(16) unsigned short SA[2][2][8192];
    __shared__ __align__(16) unsigned short SB[2][2][8192];
    const int m0 = blockIdx.x * 256;
    const int n0 = blockIdx.y * 256;
    const int tid = threadIdx.x;
    const int lane = tid & 63;
    const int wv = tid >> 6;
    const int wr = wv >> 2, wc = wv & 3;
    const int b = m0 >> 12;
    const int rbase = m0 + 1 + 2 * b;
    const int rl = lane & 15;
    const int ko0 = (lane >> 4) * 8;
    const int ko1 = 32 + ko0;
    const int blr0 = (wc & 1) * 64;
    const int rb4 = (lane >> 4) * 4;
    const int h0 = n0 >> 7;
    const int hw = h0 + (wc >> 1);

    f32x4 acc[8][4] = {};

    // ---- attn pre-pass: acc = qr(m, head cols) @ kvT^T over K=128 ----
    #pragma unroll
    for (int kt = 0; kt < 2; ++kt) {
        stage_half(&qr[(size_t)m0 * CC + h0 * DD + kt * 64], CC, SA[0][0], tid);
        stage_half(&qr[(size_t)(m0 + 128) * CC + h0 * DD + kt * 64], CC, SA[0][1], tid);
        stage_half(&qr[(size_t)m0 * CC + (h0 + 1) * DD + kt * 64], CC, SA[1][0], tid);
        stage_half(&qr[(size_t)(m0 + 128) * CC + (h0 + 1) * DD + kt * 64], CC, SA[1][1], tid);
        stage_half(&kvT[(size_t)(b * 8 + h0) * DD * DD + kt * 64], DD, SB[0][0], tid);
        stage_half(&kvT[(size_t)(b * 8 + h0) * DD * DD + (size_t)128 * DD + kt * 64], DD, SB[0][1], tid);
        __syncthreads();
        const unsigned short* Ah = SA[wc >> 1][wr];
        const unsigned short* Bh = SB[0][wc >> 1];
        bf16x8 af[4], af2[4], bfr[4], bfr2[4];
        lda4(Ah, 0, rl, ko0, af);
        lda4(Bh, blr0, rl, ko0, bfr);
        mfma_quad(acc, 0, af, bfr);
        lda4(Ah, 64, rl, ko0, af2);
        mfma_quad(acc, 4, af2, bfr);
        lda4(Ah, 0, rl, ko1, af);
        lda4(Bh, blr0, rl, ko1, bfr2);
        mfma_quad(acc, 0, af, bfr2);
        lda4(Ah, 64, rl, ko1, af2);
        mfma_quad(acc, 4, af2, bfr2);
        __syncthreads();
    }

    // ---- scale attn accumulator by z[m, hw] ----
    #pragma unroll
    for (int mf = 0; mf < 8; ++mf)
        #pragma unroll
        for (int r = 0; r < 4; ++r) {
            const float zz = z[(size_t)(m0 + wr * 128 + mf * 16 + rb4 + r) * HH + hw];
            #pragma unroll
            for (int nf = 0; nf < 4; ++nf)
                acc[mf][nf][r] *= zz;
        }
    asm volatile("s_waitcnt vmcnt(0)" ::: "memory");

    // ---- conv main loop (4-phase pipelined, NT=48) ----
    const unsigned short* Bgl = &wT[(size_t)n0 * (3 * CC)];
    // prologue: tile 0 (k0n=0 -> sh=-1, i0=0)
    {
        const unsigned short* A0 = &xpad[(size_t)(rbase - 1) * CC];
        stage_half(A0, CC, SA[0][0], tid);
        stage_half(&A0[(size_t)128 * CC], CC, SA[0][1], tid);
        stage_half(Bgl, 3 * CC, SB[0][0], tid);
        stage_half(&Bgl[(size_t)128 * (3 * CC)], 3 * CC, SB[0][1], tid);
    }
    const int NT = 48;
    for (int t = 0; t < NT; ++t) {
        const int cur = t & 1;
        const unsigned short* Ah = SA[cur][wr];
        const unsigned short* Bh = SB[cur][wc >> 1];
        const int k1 = (t + 1) * 64;
        const int sh1 = (k1 >> 10) - 1;
        const int i1 = k1 & (CC - 1);
        const unsigned short* An = &xpad[(size_t)(rbase + sh1) * CC + i1];
        KTILE_4PHASE(Ah, Bh, blr0,
            stage_half(An, CC, SA[cur ^ 1][0], tid),
            stage_half(&An[(size_t)128 * CC], CC, SA[cur ^ 1][1], tid),
            stage_half(&Bgl[k1], 3 * CC, SB[cur ^ 1][0], tid),
            stage_half(&Bgl[(size_t)128 * (3 * CC) + k1], 3 * CC, SB[cur ^ 1][1], tid),
            (t + 1 < NT));
    }

    // ---- epilogue: pure write ----
    const int col = lane & 15;
    #pragma unroll
    for (int nf = 0; nf < 4; ++nf) {
        const int n = n0 + wc * 64 + nf * 16 + col;
        const float bn = bias[n];
        #pragma unroll
        for (int mf = 0; mf < 8; ++mf)
            #pragma unroll
            for (int r = 0; r < 4; ++r) {
                const int m = m0 + wr * 128 + mf * 16 + rb4 + r;
                out[(size_t)m * CC + n] = acc[mf][nf][r] + bn;
            }
    }
}

// ---------------------------------------------------------------------------
extern "C" void kernel_launch(void* const* d_in, const int* in_sizes, int n_in,
                              void* d_out, int out_size, void* d_ws, size_t ws_size,
                              hipStream_t stream)
{
    const float* x      = (const float*)d_in[0];
    const float* qk_w   = (const float*)d_in[1];
    const float* qk_b   = (const float*)d_in[2];
    const float* lepe_w = (const float*)d_in[3];
    const float* lepe_b = (const float*)d_in[4];
    float* out = (float*)d_out;

    // fp32 region
    float* ws     = (float*)d_ws;
    float* zbuf   = ws;                                   // MM*HH
    float* ksum   = zbuf + (size_t)MM * HH;               // BB*CC
    float* kvpart = ksum + (size_t)BB * CC;               // 16*32*128*128
    // bf16 region
    unsigned short* xpad = (unsigned short*)(kvpart + (size_t)16 * 32 * DD * DD);
    unsigned short* wqT  = xpad + (size_t)BB * NP * CC;   // [2048][1024]
    unsigned short* wlT  = wqT + (size_t)2 * CC * CC;     // [1024][3072]
    unsigned short* qbuf = wlT + (size_t)CC * 3 * CC;     // M*C (q, then qr in place)
    unsigned short* kbuf = qbuf + (size_t)MM * CC;        // M*C
    unsigned short* krP  = kbuf + (size_t)MM * CC;        // [32][4096][128]
    unsigned short* kvT  = krP + (size_t)32 * NN * DD;    // [32][128e][128d]

    hipMemsetAsync(ksum, 0, BB * CC * sizeof(float), stream);

    padx_kernel          <<<BB * NP,                      256, 0, stream>>>(x, xpad);
    transpose_bf16_kernel<<<dim3(2 * CC / 32, CC / 32),   256, 0, stream>>>(qk_w, wqT, CC, 2 * CC);
    transpose_bf16_kernel<<<dim3(CC / 32, 3 * CC / 32),   256, 0, stream>>>(lepe_w, wlT, 3 * CC, CC);

    gemm_qk_mfma      <<<dim3(MM / 256, 2048 / 256), 512, 0, stream>>>(xpad, wqT, qk_b, qbuf, kbuf, ksum);
    rope_z_kernel     <<<MM / 32,                    256, 0, stream>>>(qbuf, kbuf, ksum, krP, zbuf);
    kv_kernel         <<<dim3(32, 16),               256, 0, stream>>>(krP, xpad, kvpart);
    kv_reduce_t_kernel<<<dim3(16, 32),               256, 0, stream>>>(kvpart, kvT);
    lepe_mfma         <<<dim3(MM / 256, CC / 256),   512, 0, stream>>>(xpad, wlT, lepe_b, qbuf, kvT, zbuf, out);
}

// Round 6
// 488.356 us; speedup vs baseline: 1.0669x; 1.0669x over previous
//
#include <hip/hip_runtime.h>
#include <cmath>

#define BB 4
#define NN 4096
#define CC 1024
#define HH 8
#define DD 128
#define MM (BB*NN)   // 16384
#define NP (NN+2)    // padded rows per batch

typedef __attribute__((ext_vector_type(8))) short bf16x8;
typedef __attribute__((ext_vector_type(4))) float f32x4;

static __device__ __forceinline__ unsigned short f2bf(float f) {
    unsigned int u = __float_as_uint(f);
    unsigned int r = (u + 0x7FFF + ((u >> 16) & 1)) >> 16;
    return (unsigned short)r;
}
static __device__ __forceinline__ float bf2f(short s) {
    return __uint_as_float(((unsigned int)(unsigned short)s) << 16);
}
static __device__ __forceinline__ float4 bf4(ushort4 u) {
    float4 f;
    f.x = __uint_as_float((unsigned int)u.x << 16);
    f.y = __uint_as_float((unsigned int)u.y << 16);
    f.z = __uint_as_float((unsigned int)u.z << 16);
    f.w = __uint_as_float((unsigned int)u.w << 16);
    return f;
}

static __device__ __forceinline__ void load_lds16(const void* g, void* l) {
    __builtin_amdgcn_global_load_lds(
        (const __attribute__((address_space(1))) unsigned int*)g,
        (__attribute__((address_space(3))) unsigned int*)l, 16, 0, 0);
}

// XOR bank swizzle for [*][64]-short tiles (128B rows, 8 x 16B slots/row).
static __device__ __forceinline__ int swz(int row, int ko) {
    return (row * 64 + ko) ^ ((row & 7) << 3);
}

#define CFENCE() asm volatile("" ::: "memory")
#define BAR() do { CFENCE(); __builtin_amdgcn_s_barrier(); CFENCE(); } while (0)

// ---------------------------------------------------------------------------
// P1: xpad[b][p][c] (bf16), p in [0,NP): rows 0 and NP-1 zero, p = x[b][p-1]
// ---------------------------------------------------------------------------
__global__ __launch_bounds__(256) void padx_kernel(
    const float* __restrict__ x, unsigned short* __restrict__ xpad)
{
    const int r = blockIdx.x;
    const int b = r / NP, p = r % NP;
    const int c = threadIdx.x * 4;
    ushort4 v = {0, 0, 0, 0};
    if (p >= 1 && p <= NN) {
        const float4 f = *(const float4*)&x[(size_t)(b * NN + p - 1) * CC + c];
        v.x = f2bf(f.x); v.y = f2bf(f.y); v.z = f2bf(f.z); v.w = f2bf(f.w);
    }
    *(ushort4*)&xpad[(size_t)r * CC + c] = v;
}

// ---------------------------------------------------------------------------
// P2: dst[c][r] = bf16(src[r][c])
// ---------------------------------------------------------------------------
__global__ __launch_bounds__(256) void transpose_bf16_kernel(
    const float* __restrict__ src, unsigned short* __restrict__ dst,
    int R, int Cc)
{
    __shared__ float t[32][33];
    const int r0 = blockIdx.y * 32, c0 = blockIdx.x * 32;
    const int tx = threadIdx.x & 31, ty = threadIdx.x >> 5;
    #pragma unroll
    for (int i = 0; i < 4; ++i) {
        int r = ty + i * 8;
        t[r][tx] = src[(size_t)(r0 + r) * Cc + c0 + tx];
    }
    __syncthreads();
    #pragma unroll
    for (int i = 0; i < 4; ++i) {
        int r = ty + i * 8;
        dst[(size_t)(c0 + r) * R + r0 + tx] = f2bf(t[tx][r]);
    }
}

// ---------------------------------------------------------------------------
// stage_half: one 128x64 bf16 half-tile (16KB), 512 threads x 2 x 16B loads.
// LDS dest linear (global_load_lds constraint); source slot pre-swizzled.
// ---------------------------------------------------------------------------
static __device__ __forceinline__ void stage_half(
    const unsigned short* __restrict__ g, int stride,
    unsigned short* lds, int tid)
{
    const int wb = tid & ~63;
    #pragma unroll
    for (int l = 0; l < 2; ++l) {
        const int c = l * 512 + tid;            // 0..1023
        const int row = c >> 3;                 // 0..127
        const int col8 = (c & 7) ^ (row & 7);   // inverse swizzle on source
        load_lds16(&g[(size_t)row * stride + col8 * 8],
                   &lds[(size_t)(l * 512 + wb) * 8]);
    }
}

// 4 A/B fragments (swizzled reads) from a half-tile base.
static __device__ __forceinline__ void lda4(
    const unsigned short* __restrict__ h, int lr0, int rl, int ko, bf16x8* o)
{
    #pragma unroll
    for (int i = 0; i < 4; ++i)
        o[i] = *(const bf16x8*)&h[swz(lr0 + i * 16 + rl, ko)];
}

// 16 MFMAs: one quadrant (4 mf x 4 nf), setprio-wrapped (T5).
static __device__ __forceinline__ void mfma_quad(
    f32x4 (*acc)[4], int mfb, const bf16x8* af, const bf16x8* bfr)
{
    __builtin_amdgcn_s_setprio(1);
    #pragma unroll
    for (int i = 0; i < 4; ++i)
        #pragma unroll
        for (int nf = 0; nf < 4; ++nf)
            acc[mfb + i][nf] = __builtin_amdgcn_mfma_f32_16x16x32_bf16(
                af[i], bfr[nf], acc[mfb + i][nf], 0, 0, 0);
    __builtin_amdgcn_s_setprio(0);
}

// Full BK=64 K-tile of MFMAs (64) for a wave's 128x64 sub-tile.
static __device__ __forceinline__ void mfma_ktile(
    const unsigned short* __restrict__ Ah, const unsigned short* __restrict__ Bh,
    int blr0, int rl, int kq, f32x4 acc[8][4])
{
    __builtin_amdgcn_s_setprio(1);
    #pragma unroll
    for (int ks = 0; ks < 2; ++ks) {
        const int ko = ks * 32 + kq;
        bf16x8 af[8], bfr[4];
        lda4(Ah, 0, rl, ko, af);
        lda4(Ah, 64, rl, ko, af + 4);
        lda4(Bh, blr0, rl, ko, bfr);
        #pragma unroll
        for (int mf = 0; mf < 8; ++mf)
            #pragma unroll
            for (int nf = 0; nf < 4; ++nf)
                acc[mf][nf] = __builtin_amdgcn_mfma_f32_16x16x32_bf16(
                    af[mf], bfr[nf], acc[mf][nf], 0, 0, 0);
    }
    __builtin_amdgcn_s_setprio(0);
}

// ---------------------------------------------------------------------------
// 4-phase K-tile body (lepe conv loop): per phase {ds_read | stage 1 half ->
// barrier -> 16 MFMA -> barrier}. One counted vmcnt(2) per K-tile at phase 0.
// ---------------------------------------------------------------------------
#define KTILE_4PHASE(Ah, Bh, blr0, STAGE_A0, STAGE_A1, STAGE_B0, STAGE_B1, HAVE_NEXT) \
    do {                                                                     \
        bf16x8 af_[4], af2_[4], bfr_[4], bfr2_[4];                           \
        if (HAVE_NEXT) {                                                     \
            STAGE_A0;                                                        \
            asm volatile("s_waitcnt vmcnt(2)" ::: "memory");                 \
        } else {                                                             \
            asm volatile("s_waitcnt vmcnt(0)" ::: "memory");                 \
        }                                                                    \
        BAR();                                                               \
        lda4(Ah, 0, rl, ko0, af_);                                           \
        lda4(Bh, blr0, rl, ko0, bfr_);                                       \
        mfma_quad(acc, 0, af_, bfr_);                                        \
        BAR();                                                               \
        lda4(Ah, 64, rl, ko0, af2_);                                         \
        if (HAVE_NEXT) { STAGE_A1; }                                         \
        BAR();                                                               \
        mfma_quad(acc, 4, af2_, bfr_);                                       \
        BAR();                                                               \
        lda4(Ah, 0, rl, ko1, af_);                                           \
        lda4(Bh, blr0, rl, ko1, bfr2_);                                      \
        if (HAVE_NEXT) { STAGE_B0; }                                         \
        BAR();                                                               \
        mfma_quad(acc, 0, af_, bfr2_);                                       \
        BAR();                                                               \
        lda4(Ah, 64, rl, ko1, af2_);                                         \
        if (HAVE_NEXT) { STAGE_B1; }                                         \
        BAR();                                                               \
        mfma_quad(acc, 4, af2_, bfr2_);                                      \
        BAR();                                                               \
    } while (0)

// ---------------------------------------------------------------------------
// K1: qk = x @ qk_w + qk_b ; elu+1.
// q-half: store q (bf16, for z) AND rope'd qr -> qrbuf.
// k-half: column sums -> ksum (atomic), rope'd kr -> krP directly (no kbuf).
// RoPE pairing (2j,2j+1) = adjacent n = adjacent lane -> __shfl_xor(v,1).
// K-loop: round-4 schedule (batch-stage 8 halves, counted vmcnt(8)).
// ---------------------------------------------------------------------------
__global__ __launch_bounds__(512) void gemm_qk_mfma(
    const unsigned short* __restrict__ xpad, const unsigned short* __restrict__ wT,
    const float* __restrict__ bias, unsigned short* __restrict__ qbuf,
    unsigned short* __restrict__ qrbuf, unsigned short* __restrict__ krP,
    float* __restrict__ ksum)
{
    __shared__ __align__(16) unsigned short SA[2][2][8192];
    __shared__ __align__(16) unsigned short SB[2][2][8192];
    const int m0 = blockIdx.x * 256;
    const int n0 = blockIdx.y * 256;
    const int tid = threadIdx.x;
    const int lane = tid & 63;
    const int wv = tid >> 6;
    const int wr = wv >> 2, wc = wv & 3;
    const int b = m0 >> 12;
    const int rbase = m0 + 1 + 2 * b;
    const int rl = lane & 15;
    const int kq = (lane >> 4) * 8;
    const int blr0 = (wc & 1) * 64;

    const unsigned short* Agl = &xpad[(size_t)rbase * CC];
    const unsigned short* Bgl = &wT[(size_t)n0 * CC];

    f32x4 acc[8][4] = {};
    stage_half(Agl, CC, SA[0][0], tid);
    stage_half(&Agl[(size_t)128 * CC], CC, SA[0][1], tid);
    stage_half(Bgl, CC, SB[0][0], tid);
    stage_half(&Bgl[(size_t)128 * CC], CC, SB[0][1], tid);

    const int NT = 16;
    for (int t = 0; t < NT; ++t) {
        const int cur = t & 1;
        if (t + 1 < NT) {
            const int k1 = (t + 1) * 64;
            stage_half(&Agl[k1], CC, SA[cur ^ 1][0], tid);
            stage_half(&Agl[(size_t)128 * CC + k1], CC, SA[cur ^ 1][1], tid);
            stage_half(&Bgl[k1], CC, SB[cur ^ 1][0], tid);
            stage_half(&Bgl[(size_t)128 * CC + k1], CC, SB[cur ^ 1][1], tid);
            asm volatile("s_waitcnt vmcnt(8)" ::: "memory");
        } else {
            asm volatile("s_waitcnt vmcnt(0)" ::: "memory");
        }
        BAR();
        mfma_ktile(SA[cur][wr], SB[cur][wc >> 1], blr0, rl, kq, acc);
        BAR();
    }

    const bool khalf = (n0 >= CC);
    const int col = lane & 15, rb4 = (lane >> 4) * 4;
    #pragma unroll
    for (int nf = 0; nf < 4; ++nf) {
        const int n = n0 + wc * 64 + nf * 16 + col;
        const float bn = bias[n];
        const int jpair = (khalf ? (n - CC) : n) >> 1;   // pair index 0..511
        const float theta = __builtin_exp2f((float)jpair * (-13.287712379549449f / 512.0f));
        const bool odd = (n & 1) != 0;
        float csum = 0.0f;
        #pragma unroll
        for (int mf = 0; mf < 8; ++mf)
            #pragma unroll
            for (int r = 0; r < 4; ++r) {
                const int m = m0 + wr * 128 + mf * 16 + rb4 + r;
                float v = acc[mf][nf][r] + bn;
                v = (v > 0.0f) ? (v + 1.0f) : __expf(v);   // elu(v)+1
                csum += v;
                const float p = __shfl_xor(v, 1);          // partner of the pair
                float sv, cv;
                __sincosf((float)(m & (NN - 1)) * theta, &sv, &cv);
                // even lane holds x0: pr = c*x0 - s*x1; odd holds x1: pi = c*x1 + s*x0
                const float rot = odd ? (cv * v + sv * p) : (cv * v - sv * p);
                if (!khalf) {
                    qbuf[(size_t)m * CC + n] = f2bf(v);    // pre-rope q (for z)
                    const int qcol = odd ? (512 + jpair) : jpair;
                    qrbuf[(size_t)m * CC + qcol] = f2bf(rot);
                } else {
                    const int kc = n - CC;
                    const int h = kc >> 7;                 // input head
                    const int jj = jpair & 63;
                    krP[((size_t)(b * 8 + (odd ? 4 : 0) + (h >> 1)) * NN + (m & (NN - 1))) * DD
                        + (h & 1) * 64 + jj] = f2bf(rot);
                }
            }
        if (khalf) atomicAdd(&ksum[b * CC + (n - CC)], csum);
    }
}

// ---------------------------------------------------------------------------
// K3 (slim): z[m,h] = 1/(dot(q_head, ksum_head)/N + 1e-6), pre-rope q.
// ---------------------------------------------------------------------------
__global__ __launch_bounds__(256) void z_kernel(
    const unsigned short* __restrict__ qbuf, const float* __restrict__ ksum,
    float* __restrict__ zbuf)
{
    const int tid = threadIdx.x;
    const int row = tid >> 3;            // 0..31
    const int h = tid & 7;
    const int m = blockIdx.x * 32 + row;
    const int b = m >> 12;
    const unsigned short* qrow = qbuf + (size_t)m * CC + h * DD;
    const float* km = ksum + b * CC + h * DD;
    float dot = 0.0f;
    #pragma unroll
    for (int i = 0; i < 16; ++i) {
        const bf16x8 qv = *(const bf16x8*)&qrow[i * 8];
        #pragma unroll
        for (int jq = 0; jq < 8; ++jq)
            dot = fmaf(bf2f(qv[jq]), km[i * 8 + jq], dot);
    }
    dot *= (1.0f / (float)NN);
    zbuf[(size_t)m * HH + h] = 1.0f / (dot + 1e-6f);
}

// ---------------------------------------------------------------------------
// K4: kvpart[slice][bh][d][e] = sum over slice's 256 n of kr[n,d]*v[n,e]
// ---------------------------------------------------------------------------
__global__ __launch_bounds__(256) void kv_kernel(
    const unsigned short* __restrict__ krP, const unsigned short* __restrict__ xpad,
    float* __restrict__ kvpart)
{
    __shared__ float ksm[8][132];
    __shared__ float vsm[8][132];
    const int bh = blockIdx.x;
    const int slice = blockIdx.y;
    const int b = bh >> 3, h = bh & 7;
    const int n0 = slice * 256;
    const int tid = threadIdx.x;
    const int td = (tid >> 4) * 8;
    const int te = (tid & 15) * 8;
    const unsigned short* kp = krP + ((size_t)bh * NN + n0) * DD;
    const unsigned short* vp = xpad + ((size_t)(b * NP) + 1 + n0) * CC + h * DD;
    const int sr = tid >> 5;
    const int sc = (tid & 31) * 4;
    float acc[8][8] = {};
    ushort4 kq = *(const ushort4*)&kp[(size_t)sr * DD + sc];
    ushort4 vq = *(const ushort4*)&vp[(size_t)sr * CC + sc];
    for (int r0 = 0; r0 < 256; r0 += 8) {
        *(float4*)&ksm[sr][sc] = bf4(kq);
        *(float4*)&vsm[sr][sc] = bf4(vq);
        __syncthreads();
        if (r0 + 8 < 256) {
            kq = *(const ushort4*)&kp[(size_t)(r0 + 8 + sr) * DD + sc];
            vq = *(const ushort4*)&vp[(size_t)(r0 + 8 + sr) * CC + sc];
        }
        #pragma unroll
        for (int r = 0; r < 8; ++r) {
            float a[8], bv[8];
            *(float4*)&a[0]  = *(const float4*)&ksm[r][td];
            *(float4*)&a[4]  = *(const float4*)&ksm[r][td + 4];
            *(float4*)&bv[0] = *(const float4*)&vsm[r][te];
            *(float4*)&bv[4] = *(const float4*)&vsm[r][te + 4];
            #pragma unroll
            for (int i = 0; i < 8; ++i)
                #pragma unroll
                for (int j = 0; j < 8; ++j)
                    acc[i][j] = fmaf(a[i], bv[j], acc[i][j]);
        }
        __syncthreads();
    }
    float* op = kvpart + ((size_t)slice * 32 + bh) * (DD * DD);
    #pragma unroll
    for (int i = 0; i < 8; ++i)
        #pragma unroll
        for (int j = 0; j < 8; j += 4)
            *(float4*)&op[(td + i) * DD + te + j] = *(float4*)&acc[i][j];
}

// ---------------------------------------------------------------------------
// K4b: kvT[bh][e][d] = bf16( (1/64) * sum over 16 slices kvpart[sl][bh][d][e] )
// ---------------------------------------------------------------------------
__global__ __launch_bounds__(256) void kv_reduce_t_kernel(
    const float* __restrict__ kvpart, unsigned short* __restrict__ kvT)
{
    __shared__ float t[32][33];
    const int bh = blockIdx.y;
    const int dblk = blockIdx.x >> 2, eblk = blockIdx.x & 3;
    const int tx = threadIdx.x & 31, ty = threadIdx.x >> 5;
    #pragma unroll
    for (int i = 0; i < 4; ++i) {
        const int d = dblk * 32 + ty + i * 8;
        float s = 0.0f;
        #pragma unroll
        for (int sl = 0; sl < 16; ++sl)
            s += kvpart[((size_t)sl * 32 + bh) * (DD * DD) + (size_t)d * DD + eblk * 32 + tx];
        t[ty + i * 8][tx] = s * (1.0f / 64.0f);
    }
    __syncthreads();
    #pragma unroll
    for (int i = 0; i < 4; ++i) {
        const int e = ty + i * 8;
        kvT[((size_t)bh * DD + eblk * 32 + e) * DD + dblk * 32 + tx] = f2bf(t[tx][e]);
    }
}

// ---------------------------------------------------------------------------
// K6 (fused): out = z * (qr @ kv) + conv1d(x, lepe_w, SAME) + lepe_b
// attn pre-pass (2 tiles), z-scale, then 48-tile conv loop (4-phase).
// ---------------------------------------------------------------------------
__global__ __launch_bounds__(512) void lepe_mfma(
    const unsigned short* __restrict__ xpad, const unsigned short* __restrict__ wT,
    const float* __restrict__ bias, const unsigned short* __restrict__ qr,
    const unsigned short* __restrict__ kvT, const float* __restrict__ z,
    float* __restrict__ out)
{
    __shared__ __align__(16) unsigned short SA[2][2][8192];
    __shared__ __align__(16) unsigned short SB[2][2][8192];
    const int m0 = blockIdx.x * 256;
    const int n0 = blockIdx.y * 256;
    const int tid = threadIdx.x;
    const int lane = tid & 63;
    const int wv = tid >> 6;
    const int wr = wv >> 2, wc = wv & 3;
    const int b = m0 >> 12;
    const int rbase = m0 + 1 + 2 * b;
    const int rl = lane & 15;
    const int ko0 = (lane >> 4) * 8;
    const int ko1 = 32 + ko0;
    const int blr0 = (wc & 1) * 64;
    const int rb4 = (lane >> 4) * 4;
    const int h0 = n0 >> 7;
    const int hw = h0 + (wc >> 1);

    f32x4 acc[8][4] = {};

    // ---- attn pre-pass: acc = qr(m, head cols) @ kvT^T over K=128 ----
    #pragma unroll
    for (int kt = 0; kt < 2; ++kt) {
        stage_half(&qr[(size_t)m0 * CC + h0 * DD + kt * 64], CC, SA[0][0], tid);
        stage_half(&qr[(size_t)(m0 + 128) * CC + h0 * DD + kt * 64], CC, SA[0][1], tid);
        stage_half(&qr[(size_t)m0 * CC + (h0 + 1) * DD + kt * 64], CC, SA[1][0], tid);
        stage_half(&qr[(size_t)(m0 + 128) * CC + (h0 + 1) * DD + kt * 64], CC, SA[1][1], tid);
        stage_half(&kvT[(size_t)(b * 8 + h0) * DD * DD + kt * 64], DD, SB[0][0], tid);
        stage_half(&kvT[(size_t)(b * 8 + h0) * DD * DD + (size_t)128 * DD + kt * 64], DD, SB[0][1], tid);
        __syncthreads();
        mfma_ktile(SA[wc >> 1][wr], SB[0][wc >> 1], blr0, rl, ko0, acc);
        __syncthreads();
    }

    // ---- scale attn accumulator by z[m, hw] ----
    #pragma unroll
    for (int mf = 0; mf < 8; ++mf)
        #pragma unroll
        for (int r = 0; r < 4; ++r) {
            const float zz = z[(size_t)(m0 + wr * 128 + mf * 16 + rb4 + r) * HH + hw];
            #pragma unroll
            for (int nf = 0; nf < 4; ++nf)
                acc[mf][nf][r] *= zz;
        }
    asm volatile("s_waitcnt vmcnt(0)" ::: "memory");

    // ---- conv main loop (4-phase pipelined, NT=48) ----
    const unsigned short* Bgl = &wT[(size_t)n0 * (3 * CC)];
    {
        const unsigned short* A0 = &xpad[(size_t)(rbase - 1) * CC];
        stage_half(A0, CC, SA[0][0], tid);
        stage_half(&A0[(size_t)128 * CC], CC, SA[0][1], tid);
        stage_half(Bgl, 3 * CC, SB[0][0], tid);
        stage_half(&Bgl[(size_t)128 * (3 * CC)], 3 * CC, SB[0][1], tid);
    }
    const int NT = 48;
    for (int t = 0; t < NT; ++t) {
        const int cur = t & 1;
        const unsigned short* Ah = SA[cur][wr];
        const unsigned short* Bh = SB[cur][wc >> 1];
        const int k1 = (t + 1) * 64;
        const int sh1 = (k1 >> 10) - 1;
        const int i1 = k1 & (CC - 1);
        const unsigned short* An = &xpad[(size_t)(rbase + sh1) * CC + i1];
        KTILE_4PHASE(Ah, Bh, blr0,
            stage_half(An, CC, SA[cur ^ 1][0], tid),
            stage_half(&An[(size_t)128 * CC], CC, SA[cur ^ 1][1], tid),
            stage_half(&Bgl[k1], 3 * CC, SB[cur ^ 1][0], tid),
            stage_half(&Bgl[(size_t)128 * (3 * CC) + k1], 3 * CC, SB[cur ^ 1][1], tid),
            (t + 1 < NT));
    }

    // ---- epilogue: pure write ----
    const int col = lane & 15;
    #pragma unroll
    for (int nf = 0; nf < 4; ++nf) {
        const int n = n0 + wc * 64 + nf * 16 + col;
        const float bn = bias[n];
        #pragma unroll
        for (int mf = 0; mf < 8; ++mf)
            #pragma unroll
            for (int r = 0; r < 4; ++r) {
                const int m = m0 + wr * 128 + mf * 16 + rb4 + r;
                out[(size_t)m * CC + n] = acc[mf][nf][r] + bn;
            }
    }
}

// ---------------------------------------------------------------------------
extern "C" void kernel_launch(void* const* d_in, const int* in_sizes, int n_in,
                              void* d_out, int out_size, void* d_ws, size_t ws_size,
                              hipStream_t stream)
{
    const float* x      = (const float*)d_in[0];
    const float* qk_w   = (const float*)d_in[1];
    const float* qk_b   = (const float*)d_in[2];
    const float* lepe_w = (const float*)d_in[3];
    const float* lepe_b = (const float*)d_in[4];
    float* out = (float*)d_out;

    // fp32 region
    float* ws     = (float*)d_ws;
    float* zbuf   = ws;                                   // MM*HH
    float* ksum   = zbuf + (size_t)MM * HH;               // BB*CC
    float* kvpart = ksum + (size_t)BB * CC;               // 16*32*128*128
    // bf16 region
    unsigned short* xpad  = (unsigned short*)(kvpart + (size_t)16 * 32 * DD * DD);
    unsigned short* wqT   = xpad + (size_t)BB * NP * CC;  // [2048][1024]
    unsigned short* wlT   = wqT + (size_t)2 * CC * CC;    // [1024][3072]
    unsigned short* qbuf  = wlT + (size_t)CC * 3 * CC;    // M*C pre-rope q
    unsigned short* qrbuf = qbuf + (size_t)MM * CC;       // M*C rope'd q
    unsigned short* krP   = qrbuf + (size_t)MM * CC;      // [32][4096][128]
    unsigned short* kvT   = krP + (size_t)32 * NN * DD;   // [32][128e][128d]

    hipMemsetAsync(ksum, 0, BB * CC * sizeof(float), stream);

    padx_kernel          <<<BB * NP,                      256, 0, stream>>>(x, xpad);
    transpose_bf16_kernel<<<dim3(2 * CC / 32, CC / 32),   256, 0, stream>>>(qk_w, wqT, CC, 2 * CC);
    transpose_bf16_kernel<<<dim3(CC / 32, 3 * CC / 32),   256, 0, stream>>>(lepe_w, wlT, 3 * CC, CC);

    gemm_qk_mfma      <<<dim3(MM / 256, 2048 / 256), 512, 0, stream>>>(xpad, wqT, qk_b, qbuf, qrbuf, krP, ksum);
    z_kernel          <<<MM / 32,                    256, 0, stream>>>(qbuf, ksum, zbuf);
    kv_kernel         <<<dim3(32, 16),               256, 0, stream>>>(krP, xpad, kvpart);
    kv_reduce_t_kernel<<<dim3(16, 32),               256, 0, stream>>>(kvpart, kvT);
    lepe_mfma         <<<dim3(MM / 256, CC / 256),   512, 0, stream>>>(xpad, wlT, lepe_b, qrbuf, kvT, zbuf, out);
}

// Round 8
// 440.160 us; speedup vs baseline: 1.1837x; 1.1095x over previous
//
#include <hip/hip_runtime.h>
#include <cmath>

#define BB 4
#define NN 4096
#define CC 1024
#define HH 8
#define DD 128
#define MM (BB*NN)   // 16384
#define NP (NN+2)    // padded rows per batch

typedef __attribute__((ext_vector_type(8))) short bf16x8;
typedef __attribute__((ext_vector_type(4))) float f32x4;

static __device__ __forceinline__ unsigned short f2bf(float f) {
    unsigned int u = __float_as_uint(f);
    unsigned int r = (u + 0x7FFF + ((u >> 16) & 1)) >> 16;
    return (unsigned short)r;
}
static __device__ __forceinline__ float bf2f(short s) {
    return __uint_as_float(((unsigned int)(unsigned short)s) << 16);
}
static __device__ __forceinline__ float4 bf4(ushort4 u) {
    float4 f;
    f.x = __uint_as_float((unsigned int)u.x << 16);
    f.y = __uint_as_float((unsigned int)u.y << 16);
    f.z = __uint_as_float((unsigned int)u.z << 16);
    f.w = __uint_as_float((unsigned int)u.w << 16);
    return f;
}

static __device__ __forceinline__ void load_lds16(const void* g, void* l) {
    __builtin_amdgcn_global_load_lds(
        (const __attribute__((address_space(1))) unsigned int*)g,
        (__attribute__((address_space(3))) unsigned int*)l, 16, 0, 0);
}

// XOR bank swizzle for [*][64]-short tiles (128B rows, 8 x 16B slots/row).
static __device__ __forceinline__ int swz(int row, int ko) {
    return (row * 64 + ko) ^ ((row & 7) << 3);
}

#define CFENCE() asm volatile("" ::: "memory")
#define BAR() do { CFENCE(); __builtin_amdgcn_s_barrier(); CFENCE(); } while (0)

// ---------------------------------------------------------------------------
// P1: xpad[b][p][c] (bf16), p in [0,NP): rows 0 and NP-1 zero, p = x[b][p-1]
// ---------------------------------------------------------------------------
__global__ __launch_bounds__(256) void padx_kernel(
    const float* __restrict__ x, unsigned short* __restrict__ xpad)
{
    const int r = blockIdx.x;
    const int b = r / NP, p = r % NP;
    const int c = threadIdx.x * 4;
    ushort4 v = {0, 0, 0, 0};
    if (p >= 1 && p <= NN) {
        const float4 f = *(const float4*)&x[(size_t)(b * NN + p - 1) * CC + c];
        v.x = f2bf(f.x); v.y = f2bf(f.y); v.z = f2bf(f.z); v.w = f2bf(f.w);
    }
    *(ushort4*)&xpad[(size_t)r * CC + c] = v;
}

// ---------------------------------------------------------------------------
// P2: dst[c][r] = bf16(src[r][c])
// ---------------------------------------------------------------------------
__global__ __launch_bounds__(256) void transpose_bf16_kernel(
    const float* __restrict__ src, unsigned short* __restrict__ dst,
    int R, int Cc)
{
    __shared__ float t[32][33];
    const int r0 = blockIdx.y * 32, c0 = blockIdx.x * 32;
    const int tx = threadIdx.x & 31, ty = threadIdx.x >> 5;
    #pragma unroll
    for (int i = 0; i < 4; ++i) {
        int r = ty + i * 8;
        t[r][tx] = src[(size_t)(r0 + r) * Cc + c0 + tx];
    }
    __syncthreads();
    #pragma unroll
    for (int i = 0; i < 4; ++i) {
        int r = ty + i * 8;
        dst[(size_t)(c0 + r) * R + r0 + tx] = f2bf(t[tx][r]);
    }
}

// ---------------------------------------------------------------------------
// stage_half: one 128x64 bf16 half-tile (16KB), 512 threads x 2 x 16B loads.
// ---------------------------------------------------------------------------
static __device__ __forceinline__ void stage_half(
    const unsigned short* __restrict__ g, int stride,
    unsigned short* lds, int tid)
{
    const int wb = tid & ~63;
    #pragma unroll
    for (int l = 0; l < 2; ++l) {
        const int c = l * 512 + tid;            // 0..1023
        const int row = c >> 3;                 // 0..127
        const int col8 = (c & 7) ^ (row & 7);   // inverse swizzle on source
        load_lds16(&g[(size_t)row * stride + col8 * 8],
                   &lds[(size_t)(l * 512 + wb) * 8]);
    }
}

// 4 A/B fragments (swizzled reads) from a half-tile base.
static __device__ __forceinline__ void lda4(
    const unsigned short* __restrict__ h, int lr0, int rl, int ko, bf16x8* o)
{
    #pragma unroll
    for (int i = 0; i < 4; ++i)
        o[i] = *(const bf16x8*)&h[swz(lr0 + i * 16 + rl, ko)];
}

// 16 MFMAs: one quadrant (4 mf x 4 nf), setprio-wrapped (T5).
static __device__ __forceinline__ void mfma_quad(
    f32x4 (*acc)[4], int mfb, const bf16x8* af, const bf16x8* bfr)
{
    __builtin_amdgcn_s_setprio(1);
    #pragma unroll
    for (int i = 0; i < 4; ++i)
        #pragma unroll
        for (int nf = 0; nf < 4; ++nf)
            acc[mfb + i][nf] = __builtin_amdgcn_mfma_f32_16x16x32_bf16(
                af[i], bfr[nf], acc[mfb + i][nf], 0, 0, 0);
    __builtin_amdgcn_s_setprio(0);
}

// Full BK=64 K-tile of MFMAs (64) for a wave's 128x64 sub-tile.
static __device__ __forceinline__ void mfma_ktile(
    const unsigned short* __restrict__ Ah, const unsigned short* __restrict__ Bh,
    int blr0, int rl, int kq, f32x4 acc[8][4])
{
    __builtin_amdgcn_s_setprio(1);
    #pragma unroll
    for (int ks = 0; ks < 2; ++ks) {
        const int ko = ks * 32 + kq;
        bf16x8 af[8], bfr[4];
        lda4(Ah, 0, rl, ko, af);
        lda4(Ah, 64, rl, ko, af + 4);
        lda4(Bh, blr0, rl, ko, bfr);
        #pragma unroll
        for (int mf = 0; mf < 8; ++mf)
            #pragma unroll
            for (int nf = 0; nf < 4; ++nf)
                acc[mf][nf] = __builtin_amdgcn_mfma_f32_16x16x32_bf16(
                    af[mf], bfr[nf], acc[mf][nf], 0, 0, 0);
    }
    __builtin_amdgcn_s_setprio(0);
}

// ---------------------------------------------------------------------------
// 4-phase K-tile body (lepe conv loop).
// ---------------------------------------------------------------------------
#define KTILE_4PHASE(Ah, Bh, blr0, STAGE_A0, STAGE_A1, STAGE_B0, STAGE_B1, HAVE_NEXT) \
    do {                                                                     \
        bf16x8 af_[4], af2_[4], bfr_[4], bfr2_[4];                           \
        if (HAVE_NEXT) {                                                     \
            STAGE_A0;                                                        \
            asm volatile("s_waitcnt vmcnt(2)" ::: "memory");                 \
        } else {                                                             \
            asm volatile("s_waitcnt vmcnt(0)" ::: "memory");                 \
        }                                                                    \
        BAR();                                                               \
        lda4(Ah, 0, rl, ko0, af_);                                           \
        lda4(Bh, blr0, rl, ko0, bfr_);                                       \
        mfma_quad(acc, 0, af_, bfr_);                                        \
        BAR();                                                               \
        lda4(Ah, 64, rl, ko0, af2_);                                         \
        if (HAVE_NEXT) { STAGE_A1; }                                         \
        BAR();                                                               \
        mfma_quad(acc, 4, af2_, bfr_);                                       \
        BAR();                                                               \
        lda4(Ah, 0, rl, ko1, af_);                                           \
        lda4(Bh, blr0, rl, ko1, bfr2_);                                      \
        if (HAVE_NEXT) { STAGE_B0; }                                         \
        BAR();                                                               \
        mfma_quad(acc, 0, af_, bfr2_);                                       \
        BAR();                                                               \
        lda4(Ah, 64, rl, ko1, af2_);                                         \
        if (HAVE_NEXT) { STAGE_B1; }                                         \
        BAR();                                                               \
        mfma_quad(acc, 4, af2_, bfr2_);                                      \
        BAR();                                                               \
    } while (0)

// ---------------------------------------------------------------------------
// K1: qk = x @ qk_w + qk_b ; elu+1 ; RoPE fused.
// q-half: rope'd qr -> qrbuf (concat pr|pi layout). No pre-rope q stored
// (z_kernel rotates ksum instead: q.km == (Rq).(Rkm), R orthogonal).
// k-half: column sums -> ksum (atomic); rope'd kr -> krP.
// Epilogue: LDS-staged T[256][256] -> fully coalesced 256B-row writes.
// LDS sub-buffers addressed via inline offsets (no static pointer arrays:
// addrspacecast static initializers don't compile on gfx950).
// ---------------------------------------------------------------------------
__global__ __launch_bounds__(512) void gemm_qk_mfma(
    const unsigned short* __restrict__ xpad, const unsigned short* __restrict__ wT,
    const float* __restrict__ bias, unsigned short* __restrict__ qrbuf,
    unsigned short* __restrict__ krP, float* __restrict__ ksum)
{
    __shared__ __align__(16) unsigned short SMEM[65536];   // 128KB
    // layout: A[buf][half] at buf*16384 + half*8192; B at +32768
    #define SAP(buf, half) (&SMEM[(buf) * 16384 + (half) * 8192])
    #define SBP(buf, half) (&SMEM[32768 + (buf) * 16384 + (half) * 8192])
    const int m0 = blockIdx.x * 256;
    const int n0 = blockIdx.y * 256;
    const int tid = threadIdx.x;
    const int lane = tid & 63;
    const int wv = tid >> 6;
    const int wr = wv >> 2, wc = wv & 3;
    const int b = m0 >> 12;
    const int rbase = m0 + 1 + 2 * b;
    const int rl = lane & 15;
    const int kq = (lane >> 4) * 8;
    const int blr0 = (wc & 1) * 64;

    const unsigned short* Agl = &xpad[(size_t)rbase * CC];
    const unsigned short* Bgl = &wT[(size_t)n0 * CC];

    f32x4 acc[8][4] = {};
    stage_half(Agl, CC, SAP(0, 0), tid);
    stage_half(&Agl[(size_t)128 * CC], CC, SAP(0, 1), tid);
    stage_half(Bgl, CC, SBP(0, 0), tid);
    stage_half(&Bgl[(size_t)128 * CC], CC, SBP(0, 1), tid);

    const int NT = 16;
    for (int t = 0; t < NT; ++t) {
        const int cur = t & 1;
        if (t + 1 < NT) {
            const int k1 = (t + 1) * 64;
            stage_half(&Agl[k1], CC, SAP(cur ^ 1, 0), tid);
            stage_half(&Agl[(size_t)128 * CC + k1], CC, SAP(cur ^ 1, 1), tid);
            stage_half(&Bgl[k1], CC, SBP(cur ^ 1, 0), tid);
            stage_half(&Bgl[(size_t)128 * CC + k1], CC, SBP(cur ^ 1, 1), tid);
            asm volatile("s_waitcnt vmcnt(8)" ::: "memory");
        } else {
            asm volatile("s_waitcnt vmcnt(0)" ::: "memory");
        }
        BAR();
        mfma_ktile(SAP(cur, wr), SBP(cur, wc >> 1), blr0, rl, kq, acc);
        BAR();
    }

    // ---- epilogue: elu+1, RoPE, LDS-stage into T[256][256] ----
    unsigned short* T = SMEM;                  // reuse (vmcnt==0, post-barrier)
    const bool khalf = (n0 >= CC);
    const int col = lane & 15, rb4 = (lane >> 4) * 4;
    const int pos0 = m0 & (NN - 1);
    const int P = b * 8 + (khalf ? ((n0 - CC) >> 8) : 0);

    #pragma unroll
    for (int nf = 0; nf < 4; ++nf) {
        const int lcol = wc * 64 + nf * 16 + col;
        const int n = n0 + lcol;
        const float bn = bias[n];
        const int jpair = (khalf ? (n - CC) : n) >> 1;
        const float theta = __builtin_exp2f((float)jpair * (-13.287712379549449f / 512.0f));
        const bool odd = (n & 1) != 0;
        float csum = 0.0f;
        #pragma unroll
        for (int mf = 0; mf < 8; ++mf)
            #pragma unroll
            for (int r = 0; r < 4; ++r) {
                const int lrow = wr * 128 + mf * 16 + rb4 + r;
                const int m = m0 + lrow;
                float v = acc[mf][nf][r] + bn;
                v = (v > 0.0f) ? (v + 1.0f) : __expf(v);   // elu(v)+1
                csum += v;
                const float p = __shfl_xor(v, 1);          // pair partner
                float sv, cv;
                __sincosf((float)(m & (NN - 1)) * theta, &sv, &cv);
                const float rot = odd ? (cv * v + sv * p) : (cv * v - sv * p);
                T[lrow * 256 + (odd ? 128 : 0) + (lcol >> 1)] = f2bf(rot);
            }
        if (khalf) atomicAdd(&ksum[b * CC + (n - CC)], csum);
    }
    __syncthreads();   // T fully staged

    // ---- 16 coalesced passes: each 16B chunk of a 256B output row ----
    #pragma unroll
    for (int pss = 0; pss < 16; ++pss) {
        const int ch = pss * 512 + tid;
        const int row = ch >> 5;               // 0..255
        const int cx = ch & 31;                // 16B chunk in 512B LDS row
        const int stripe = cx >> 4;            // 0 = even(pr/plane P), 1 = odd
        const int c8 = (cx & 15) * 8;          // ushort offset in stripe
        const bf16x8 w = *(const bf16x8*)&T[row * 256 + cx * 8];
        if (!khalf)
            *(bf16x8*)&qrbuf[(size_t)(m0 + row) * CC + stripe * 512 + (n0 >> 1) + c8] = w;
        else
            *(bf16x8*)&krP[((size_t)(P + stripe * 4) * NN + pos0 + row) * DD + c8] = w;
    }
    #undef SAP
    #undef SBP
}

// ---------------------------------------------------------------------------
// K3: z[m,h] = 1/(dot(qr, R(m)ksum)/N + 1e-6)  (R orthogonal: == q.ksum)
// ---------------------------------------------------------------------------
__global__ __launch_bounds__(256) void z_kernel(
    const unsigned short* __restrict__ qr, const float* __restrict__ ksum,
    float* __restrict__ zbuf)
{
    const int tid = threadIdx.x;
    const int row = tid >> 3;            // 0..31
    const int h = tid & 7;
    const int m = blockIdx.x * 32 + row;
    const int b = m >> 12;
    const int pos = m & (NN - 1);
    const unsigned short* qe = qr + (size_t)m * CC + h * 64;        // pr stripe
    const unsigned short* qo = qe + 512;                            // pi stripe
    const float* km = ksum + b * CC + h * DD;
    float dot = 0.0f;
    #pragma unroll
    for (int j8 = 0; j8 < 8; ++j8) {
        const bf16x8 ev = *(const bf16x8*)&qe[j8 * 8];
        const bf16x8 ov = *(const bf16x8*)&qo[j8 * 8];
        #pragma unroll
        for (int u = 0; u < 8; ++u) {
            const int jj = j8 * 8 + u;
            const int jg = h * 64 + jj;
            const float theta = __builtin_exp2f((float)jg * (-13.287712379549449f / 512.0f));
            float sv, cv;
            __sincosf((float)pos * theta, &sv, &cv);
            const float k0 = km[2 * jj], k1 = km[2 * jj + 1];
            dot = fmaf(bf2f(ev[u]), cv * k0 - sv * k1, dot);
            dot = fmaf(bf2f(ov[u]), cv * k1 + sv * k0, dot);
        }
    }
    dot *= (1.0f / (float)NN);
    zbuf[(size_t)m * HH + h] = 1.0f / (dot + 1e-6f);
}

// ---------------------------------------------------------------------------
// K4: kvpart[slice][bh][d][e] = sum over slice's 256 n of kr[n,d]*v[n,e]
// ---------------------------------------------------------------------------
__global__ __launch_bounds__(256) void kv_kernel(
    const unsigned short* __restrict__ krP, const unsigned short* __restrict__ xpad,
    float* __restrict__ kvpart)
{
    __shared__ float ksm[8][132];
    __shared__ float vsm[8][132];
    const int bh = blockIdx.x;
    const int slice = blockIdx.y;
    const int b = bh >> 3, h = bh & 7;
    const int n0 = slice * 256;
    const int tid = threadIdx.x;
    const int td = (tid >> 4) * 8;
    const int te = (tid & 15) * 8;
    const unsigned short* kp = krP + ((size_t)bh * NN + n0) * DD;
    const unsigned short* vp = xpad + ((size_t)(b * NP) + 1 + n0) * CC + h * DD;
    const int sr = tid >> 5;
    const int sc = (tid & 31) * 4;
    float acc[8][8] = {};
    ushort4 kq = *(const ushort4*)&kp[(size_t)sr * DD + sc];
    ushort4 vq = *(const ushort4*)&vp[(size_t)sr * CC + sc];
    for (int r0 = 0; r0 < 256; r0 += 8) {
        *(float4*)&ksm[sr][sc] = bf4(kq);
        *(float4*)&vsm[sr][sc] = bf4(vq);
        __syncthreads();
        if (r0 + 8 < 256) {
            kq = *(const ushort4*)&kp[(size_t)(r0 + 8 + sr) * DD + sc];
            vq = *(const ushort4*)&vp[(size_t)(r0 + 8 + sr) * CC + sc];
        }
        #pragma unroll
        for (int r = 0; r < 8; ++r) {
            float a[8], bv[8];
            *(float4*)&a[0]  = *(const float4*)&ksm[r][td];
            *(float4*)&a[4]  = *(const float4*)&ksm[r][td + 4];
            *(float4*)&bv[0] = *(const float4*)&vsm[r][te];
            *(float4*)&bv[4] = *(const float4*)&vsm[r][te + 4];
            #pragma unroll
            for (int i = 0; i < 8; ++i)
                #pragma unroll
                for (int j = 0; j < 8; ++j)
                    acc[i][j] = fmaf(a[i], bv[j], acc[i][j]);
        }
        __syncthreads();
    }
    float* op = kvpart + ((size_t)slice * 32 + bh) * (DD * DD);
    #pragma unroll
    for (int i = 0; i < 8; ++i)
        #pragma unroll
        for (int j = 0; j < 8; j += 4)
            *(float4*)&op[(td + i) * DD + te + j] = *(float4*)&acc[i][j];
}

// ---------------------------------------------------------------------------
// K4b: kvT[bh][e][d] = bf16( (1/64) * sum over 16 slices kvpart[sl][bh][d][e] )
// ---------------------------------------------------------------------------
__global__ __launch_bounds__(256) void kv_reduce_t_kernel(
    const float* __restrict__ kvpart, unsigned short* __restrict__ kvT)
{
    __shared__ float t[32][33];
    const int bh = blockIdx.y;
    const int dblk = blockIdx.x >> 2, eblk = blockIdx.x & 3;
    const int tx = threadIdx.x & 31, ty = threadIdx.x >> 5;
    #pragma unroll
    for (int i = 0; i < 4; ++i) {
        const int d = dblk * 32 + ty + i * 8;
        float s = 0.0f;
        #pragma unroll
        for (int sl = 0; sl < 16; ++sl)
            s += kvpart[((size_t)sl * 32 + bh) * (DD * DD) + (size_t)d * DD + eblk * 32 + tx];
        t[ty + i * 8][tx] = s * (1.0f / 64.0f);
    }
    __syncthreads();
    #pragma unroll
    for (int i = 0; i < 4; ++i) {
        const int e = ty + i * 8;
        kvT[((size_t)bh * DD + eblk * 32 + e) * DD + dblk * 32 + tx] = f2bf(t[tx][e]);
    }
}

// ---------------------------------------------------------------------------
// K6 (fused): out = z * (qr @ kv) + conv1d(x, lepe_w, SAME) + lepe_b
// ---------------------------------------------------------------------------
__global__ __launch_bounds__(512) void lepe_mfma(
    const unsigned short* __restrict__ xpad, const unsigned short* __restrict__ wT,
    const float* __restrict__ bias, const unsigned short* __restrict__ qr,
    const unsigned short* __restrict__ kvT, const float* __restrict__ z,
    float* __restrict__ out)
{
    __shared__ __align__(16) unsigned short SA[2][2][8192];
    __shared__ __align__(16) unsigned short SB[2][2][8192];
    const int m0 = blockIdx.x * 256;
    const int n0 = blockIdx.y * 256;
    const int tid = threadIdx.x;
    const int lane = tid & 63;
    const int wv = tid >> 6;
    const int wr = wv >> 2, wc = wv & 3;
    const int b = m0 >> 12;
    const int rbase = m0 + 1 + 2 * b;
    const int rl = lane & 15;
    const int ko0 = (lane >> 4) * 8;
    const int ko1 = 32 + ko0;
    const int blr0 = (wc & 1) * 64;
    const int rb4 = (lane >> 4) * 4;
    const int h0 = n0 >> 7;
    const int hw = h0 + (wc >> 1);

    f32x4 acc[8][4] = {};

    // ---- attn pre-pass: acc = qr(m, head cols) @ kvT^T over K=128 ----
    #pragma unroll
    for (int kt = 0; kt < 2; ++kt) {
        stage_half(&qr[(size_t)m0 * CC + h0 * DD + kt * 64], CC, SA[0][0], tid);
        stage_half(&qr[(size_t)(m0 + 128) * CC + h0 * DD + kt * 64], CC, SA[0][1], tid);
        stage_half(&qr[(size_t)m0 * CC + (h0 + 1) * DD + kt * 64], CC, SA[1][0], tid);
        stage_half(&qr[(size_t)(m0 + 128) * CC + (h0 + 1) * DD + kt * 64], CC, SA[1][1], tid);
        stage_half(&kvT[(size_t)(b * 8 + h0) * DD * DD + kt * 64], DD, SB[0][0], tid);
        stage_half(&kvT[(size_t)(b * 8 + h0) * DD * DD + (size_t)128 * DD + kt * 64], DD, SB[0][1], tid);
        __syncthreads();
        mfma_ktile(SA[wc >> 1][wr], SB[0][wc >> 1], blr0, rl, ko0, acc);
        __syncthreads();
    }

    // ---- scale attn accumulator by z[m, hw] ----
    #pragma unroll
    for (int mf = 0; mf < 8; ++mf)
        #pragma unroll
        for (int r = 0; r < 4; ++r) {
            const float zz = z[(size_t)(m0 + wr * 128 + mf * 16 + rb4 + r) * HH + hw];
            #pragma unroll
            for (int nf = 0; nf < 4; ++nf)
                acc[mf][nf][r] *= zz;
        }
    asm volatile("s_waitcnt vmcnt(0)" ::: "memory");

    // ---- conv main loop (4-phase pipelined, NT=48) ----
    const unsigned short* Bgl = &wT[(size_t)n0 * (3 * CC)];
    {
        const unsigned short* A0 = &xpad[(size_t)(rbase - 1) * CC];
        stage_half(A0, CC, SA[0][0], tid);
        stage_half(&A0[(size_t)128 * CC], CC, SA[0][1], tid);
        stage_half(Bgl, 3 * CC, SB[0][0], tid);
        stage_half(&Bgl[(size_t)128 * (3 * CC)], 3 * CC, SB[0][1], tid);
    }
    const int NT = 48;
    for (int t = 0; t < NT; ++t) {
        const int cur = t & 1;
        const unsigned short* Ah = SA[cur][wr];
        const unsigned short* Bh = SB[cur][wc >> 1];
        const int k1 = (t + 1) * 64;
        const int sh1 = (k1 >> 10) - 1;
        const int i1 = k1 & (CC - 1);
        const unsigned short* An = &xpad[(size_t)(rbase + sh1) * CC + i1];
        KTILE_4PHASE(Ah, Bh, blr0,
            stage_half(An, CC, SA[cur ^ 1][0], tid),
            stage_half(&An[(size_t)128 * CC], CC, SA[cur ^ 1][1], tid),
            stage_half(&Bgl[k1], 3 * CC, SB[cur ^ 1][0], tid),
            stage_half(&Bgl[(size_t)128 * (3 * CC) + k1], 3 * CC, SB[cur ^ 1][1], tid),
            (t + 1 < NT));
    }

    // ---- epilogue: pure write ----
    const int col = lane & 15;
    #pragma unroll
    for (int nf = 0; nf < 4; ++nf) {
        const int n = n0 + wc * 64 + nf * 16 + col;
        const float bn = bias[n];
        #pragma unroll
        for (int mf = 0; mf < 8; ++mf)
            #pragma unroll
            for (int r = 0; r < 4; ++r) {
                const int m = m0 + wr * 128 + mf * 16 + rb4 + r;
                out[(size_t)m * CC + n] = acc[mf][nf][r] + bn;
            }
    }
}

// ---------------------------------------------------------------------------
extern "C" void kernel_launch(void* const* d_in, const int* in_sizes, int n_in,
                              void* d_out, int out_size, void* d_ws, size_t ws_size,
                              hipStream_t stream)
{
    const float* x      = (const float*)d_in[0];
    const float* qk_w   = (const float*)d_in[1];
    const float* qk_b   = (const float*)d_in[2];
    const float* lepe_w = (const float*)d_in[3];
    const float* lepe_b = (const float*)d_in[4];
    float* out = (float*)d_out;

    // fp32 region
    float* ws     = (float*)d_ws;
    float* zbuf   = ws;                                   // MM*HH
    float* ksum   = zbuf + (size_t)MM * HH;               // BB*CC
    float* kvpart = ksum + (size_t)BB * CC;               // 16*32*128*128
    // bf16 region
    unsigned short* xpad  = (unsigned short*)(kvpart + (size_t)16 * 32 * DD * DD);
    unsigned short* wqT   = xpad + (size_t)BB * NP * CC;  // [2048][1024]
    unsigned short* wlT   = wqT + (size_t)2 * CC * CC;    // [1024][3072]
    unsigned short* qrbuf = wlT + (size_t)CC * 3 * CC;    // M*C rope'd q
    unsigned short* krP   = qrbuf + (size_t)MM * CC;      // [32][4096][128]
    unsigned short* kvT   = krP + (size_t)32 * NN * DD;   // [32][128e][128d]

    (void)hipMemsetAsync(ksum, 0, BB * CC * sizeof(float), stream);

    padx_kernel          <<<BB * NP,                      256, 0, stream>>>(x, xpad);
    transpose_bf16_kernel<<<dim3(2 * CC / 32, CC / 32),   256, 0, stream>>>(qk_w, wqT, CC, 2 * CC);
    transpose_bf16_kernel<<<dim3(CC / 32, 3 * CC / 32),   256, 0, stream>>>(lepe_w, wlT, 3 * CC, CC);

    gemm_qk_mfma      <<<dim3(MM / 256, 2048 / 256), 512, 0, stream>>>(xpad, wqT, qk_b, qrbuf, krP, ksum);
    z_kernel          <<<MM / 32,                    256, 0, stream>>>(qrbuf, ksum, zbuf);
    kv_kernel         <<<dim3(32, 16),               256, 0, stream>>>(krP, xpad, kvpart);
    kv_reduce_t_kernel<<<dim3(16, 32),               256, 0, stream>>>(kvpart, kvT);
    lepe_mfma         <<<dim3(MM / 256, CC / 256),   512, 0, stream>>>(xpad, wlT, lepe_b, qrbuf, kvT, zbuf, out);
}

// Round 9
// 437.879 us; speedup vs baseline: 1.1899x; 1.0052x over previous
//
#include <hip/hip_runtime.h>
#include <cmath>

#define BB 4
#define NN 4096
#define CC 1024
#define HH 8
#define DD 128
#define MM (BB*NN)   // 16384
#define NP (NN+2)    // padded rows per batch

typedef __attribute__((ext_vector_type(8))) short bf16x8;
typedef __attribute__((ext_vector_type(4))) float f32x4;

static __device__ __forceinline__ unsigned short f2bf(float f) {
    unsigned int u = __float_as_uint(f);
    unsigned int r = (u + 0x7FFF + ((u >> 16) & 1)) >> 16;
    return (unsigned short)r;
}
static __device__ __forceinline__ float bf2f(short s) {
    return __uint_as_float(((unsigned int)(unsigned short)s) << 16);
}
static __device__ __forceinline__ float4 bf4(ushort4 u) {
    float4 f;
    f.x = __uint_as_float((unsigned int)u.x << 16);
    f.y = __uint_as_float((unsigned int)u.y << 16);
    f.z = __uint_as_float((unsigned int)u.z << 16);
    f.w = __uint_as_float((unsigned int)u.w << 16);
    return f;
}

static __device__ __forceinline__ void load_lds16(const void* g, void* l) {
    __builtin_amdgcn_global_load_lds(
        (const __attribute__((address_space(1))) unsigned int*)g,
        (__attribute__((address_space(3))) unsigned int*)l, 16, 0, 0);
}

// XOR bank swizzle for [*][64]-short tiles (128B rows, 8 x 16B slots/row).
static __device__ __forceinline__ int swz(int row, int ko) {
    return (row * 64 + ko) ^ ((row & 7) << 3);
}

#define CFENCE() asm volatile("" ::: "memory")
#define BAR() do { CFENCE(); __builtin_amdgcn_s_barrier(); CFENCE(); } while (0)

// ---------------------------------------------------------------------------
// P1: xpad[b][p][c] (bf16), p in [0,NP): rows 0 and NP-1 zero, p = x[b][p-1]
// ---------------------------------------------------------------------------
__global__ __launch_bounds__(256) void padx_kernel(
    const float* __restrict__ x, unsigned short* __restrict__ xpad)
{
    const int r = blockIdx.x;
    const int b = r / NP, p = r % NP;
    const int c = threadIdx.x * 4;
    ushort4 v = {0, 0, 0, 0};
    if (p >= 1 && p <= NN) {
        const float4 f = *(const float4*)&x[(size_t)(b * NN + p - 1) * CC + c];
        v.x = f2bf(f.x); v.y = f2bf(f.y); v.z = f2bf(f.z); v.w = f2bf(f.w);
    }
    *(ushort4*)&xpad[(size_t)r * CC + c] = v;
}

// ---------------------------------------------------------------------------
// P2: dst[c][r] = bf16(src[r][c])
// ---------------------------------------------------------------------------
__global__ __launch_bounds__(256) void transpose_bf16_kernel(
    const float* __restrict__ src, unsigned short* __restrict__ dst,
    int R, int Cc)
{
    __shared__ float t[32][33];
    const int r0 = blockIdx.y * 32, c0 = blockIdx.x * 32;
    const int tx = threadIdx.x & 31, ty = threadIdx.x >> 5;
    #pragma unroll
    for (int i = 0; i < 4; ++i) {
        int r = ty + i * 8;
        t[r][tx] = src[(size_t)(r0 + r) * Cc + c0 + tx];
    }
    __syncthreads();
    #pragma unroll
    for (int i = 0; i < 4; ++i) {
        int r = ty + i * 8;
        dst[(size_t)(c0 + r) * R + r0 + tx] = f2bf(t[tx][r]);
    }
}

// ---------------------------------------------------------------------------
// stage_half: one 128x64 bf16 half-tile (16KB), 512 threads x 2 x 16B loads.
// ---------------------------------------------------------------------------
static __device__ __forceinline__ void stage_half(
    const unsigned short* __restrict__ g, int stride,
    unsigned short* lds, int tid)
{
    const int wb = tid & ~63;
    #pragma unroll
    for (int l = 0; l < 2; ++l) {
        const int c = l * 512 + tid;            // 0..1023
        const int row = c >> 3;                 // 0..127
        const int col8 = (c & 7) ^ (row & 7);   // inverse swizzle on source
        load_lds16(&g[(size_t)row * stride + col8 * 8],
                   &lds[(size_t)(l * 512 + wb) * 8]);
    }
}

// 4 A/B fragments (swizzled reads) from a half-tile base.
static __device__ __forceinline__ void lda4(
    const unsigned short* __restrict__ h, int lr0, int rl, int ko, bf16x8* o)
{
    #pragma unroll
    for (int i = 0; i < 4; ++i)
        o[i] = *(const bf16x8*)&h[swz(lr0 + i * 16 + rl, ko)];
}

// 16 MFMAs: one quadrant (4 mf x 4 nf), setprio-wrapped (T5).
static __device__ __forceinline__ void mfma_quad(
    f32x4 (*acc)[4], int mfb, const bf16x8* af, const bf16x8* bfr)
{
    __builtin_amdgcn_s_setprio(1);
    #pragma unroll
    for (int i = 0; i < 4; ++i)
        #pragma unroll
        for (int nf = 0; nf < 4; ++nf)
            acc[mfb + i][nf] = __builtin_amdgcn_mfma_f32_16x16x32_bf16(
                af[i], bfr[nf], acc[mfb + i][nf], 0, 0, 0);
    __builtin_amdgcn_s_setprio(0);
}

// Full BK=64 K-tile of MFMAs (64) for a wave's 128x64 sub-tile (attn pre-pass).
static __device__ __forceinline__ void mfma_ktile(
    const unsigned short* __restrict__ Ah, const unsigned short* __restrict__ Bh,
    int blr0, int rl, int kq, f32x4 acc[8][4])
{
    __builtin_amdgcn_s_setprio(1);
    #pragma unroll
    for (int ks = 0; ks < 2; ++ks) {
        const int ko = ks * 32 + kq;
        bf16x8 af[8], bfr[4];
        lda4(Ah, 0, rl, ko, af);
        lda4(Ah, 64, rl, ko, af + 4);
        lda4(Bh, blr0, rl, ko, bfr);
        #pragma unroll
        for (int mf = 0; mf < 8; ++mf)
            #pragma unroll
            for (int nf = 0; nf < 4; ++nf)
                acc[mf][nf] = __builtin_amdgcn_mfma_f32_16x16x32_bf16(
                    af[mf], bfr[nf], acc[mf][nf], 0, 0, 0);
    }
    __builtin_amdgcn_s_setprio(0);
}

// ---------------------------------------------------------------------------
// Burst-stage 4-phase K-tile body: ALL 8 next-tile loads issue at phase 0
// (each gets the full 4-phase ~1000cy landing window), counted vmcnt(8)
// waits exactly for the CURRENT tile's 8 loads (issued one K-tile earlier).
// Then 4 phases of {ds_read | barrier | 16 MFMA | barrier} fine interleave.
// ---------------------------------------------------------------------------
#define KTILE_4PHASE(Ah, Bh, blr0, STAGE_ALL, HAVE_NEXT)                     \
    do {                                                                     \
        bf16x8 af_[4], af2_[4], bfr_[4], bfr2_[4];                           \
        if (HAVE_NEXT) {                                                     \
            STAGE_ALL;                                                       \
            asm volatile("s_waitcnt vmcnt(8)" ::: "memory");                 \
        } else {                                                             \
            asm volatile("s_waitcnt vmcnt(0)" ::: "memory");                 \
        }                                                                    \
        BAR();                                                               \
        lda4(Ah, 0, rl, ko0, af_);                                           \
        lda4(Bh, blr0, rl, ko0, bfr_);                                       \
        mfma_quad(acc, 0, af_, bfr_);                                        \
        BAR();                                                               \
        lda4(Ah, 64, rl, ko0, af2_);                                         \
        BAR();                                                               \
        mfma_quad(acc, 4, af2_, bfr_);                                       \
        BAR();                                                               \
        lda4(Ah, 0, rl, ko1, af_);                                           \
        lda4(Bh, blr0, rl, ko1, bfr2_);                                      \
        BAR();                                                               \
        mfma_quad(acc, 0, af_, bfr2_);                                       \
        BAR();                                                               \
        lda4(Ah, 64, rl, ko1, af2_);                                         \
        BAR();                                                               \
        mfma_quad(acc, 4, af2_, bfr2_);                                      \
        BAR();                                                               \
    } while (0)

// ---------------------------------------------------------------------------
// K1: qk = x @ qk_w + qk_b ; elu+1 ; RoPE fused.
// q-half: rope'd qr -> qrbuf (concat pr|pi layout). k-half: ksum atomics +
// rope'd kr -> krP. Coalesced LDS-staged epilogue (T[256][256]).
// K-loop: burst-stage + 4-phase interleave.
// ---------------------------------------------------------------------------
__global__ __launch_bounds__(512) void gemm_qk_mfma(
    const unsigned short* __restrict__ xpad, const unsigned short* __restrict__ wT,
    const float* __restrict__ bias, unsigned short* __restrict__ qrbuf,
    unsigned short* __restrict__ krP, float* __restrict__ ksum)
{
    __shared__ __align__(16) unsigned short SMEM[65536];   // 128KB
    #define SAP(buf, half) (&SMEM[(buf) * 16384 + (half) * 8192])
    #define SBP(buf, half) (&SMEM[32768 + (buf) * 16384 + (half) * 8192])
    const int m0 = blockIdx.x * 256;
    const int n0 = blockIdx.y * 256;
    const int tid = threadIdx.x;
    const int lane = tid & 63;
    const int wv = tid >> 6;
    const int wr = wv >> 2, wc = wv & 3;
    const int b = m0 >> 12;
    const int rbase = m0 + 1 + 2 * b;
    const int rl = lane & 15;
    const int ko0 = (lane >> 4) * 8;
    const int ko1 = 32 + ko0;
    const int blr0 = (wc & 1) * 64;

    const unsigned short* Agl = &xpad[(size_t)rbase * CC];
    const unsigned short* Bgl = &wT[(size_t)n0 * CC];

    f32x4 acc[8][4] = {};
    stage_half(Agl, CC, SAP(0, 0), tid);
    stage_half(&Agl[(size_t)128 * CC], CC, SAP(0, 1), tid);
    stage_half(Bgl, CC, SBP(0, 0), tid);
    stage_half(&Bgl[(size_t)128 * CC], CC, SBP(0, 1), tid);

    const int NT = 16;
    for (int t = 0; t < NT; ++t) {
        const int cur = t & 1;
        const int k1 = (t + 1) * 64;
        KTILE_4PHASE(SAP(cur, wr), SBP(cur, wc >> 1), blr0,
            { stage_half(&Agl[k1], CC, SAP(cur ^ 1, 0), tid);
              stage_half(&Agl[(size_t)128 * CC + k1], CC, SAP(cur ^ 1, 1), tid);
              stage_half(&Bgl[k1], CC, SBP(cur ^ 1, 0), tid);
              stage_half(&Bgl[(size_t)128 * CC + k1], CC, SBP(cur ^ 1, 1), tid); },
            (t + 1 < NT));
    }

    // ---- epilogue: elu+1, RoPE, LDS-stage into T[256][256] ----
    unsigned short* T = SMEM;                  // reuse (vmcnt==0, post-barrier)
    const bool khalf = (n0 >= CC);
    const int col = lane & 15, rb4 = (lane >> 4) * 4;
    const int pos0 = m0 & (NN - 1);
    const int P = b * 8 + (khalf ? ((n0 - CC) >> 8) : 0);

    #pragma unroll
    for (int nf = 0; nf < 4; ++nf) {
        const int lcol = wc * 64 + nf * 16 + col;
        const int n = n0 + lcol;
        const float bn = bias[n];
        const int jpair = (khalf ? (n - CC) : n) >> 1;
        const float theta = __builtin_exp2f((float)jpair * (-13.287712379549449f / 512.0f));
        const bool odd = (n & 1) != 0;
        float csum = 0.0f;
        #pragma unroll
        for (int mf = 0; mf < 8; ++mf)
            #pragma unroll
            for (int r = 0; r < 4; ++r) {
                const int lrow = wr * 128 + mf * 16 + rb4 + r;
                const int m = m0 + lrow;
                float v = acc[mf][nf][r] + bn;
                v = (v > 0.0f) ? (v + 1.0f) : __expf(v);   // elu(v)+1
                csum += v;
                const float p = __shfl_xor(v, 1);          // pair partner
                float sv, cv;
                __sincosf((float)(m & (NN - 1)) * theta, &sv, &cv);
                const float rot = odd ? (cv * v + sv * p) : (cv * v - sv * p);
                T[lrow * 256 + (odd ? 128 : 0) + (lcol >> 1)] = f2bf(rot);
            }
        if (khalf) atomicAdd(&ksum[b * CC + (n - CC)], csum);
    }
    __syncthreads();   // T fully staged

    // ---- 16 coalesced passes: each 16B chunk of a 256B output row ----
    #pragma unroll
    for (int pss = 0; pss < 16; ++pss) {
        const int ch = pss * 512 + tid;
        const int row = ch >> 5;               // 0..255
        const int cx = ch & 31;                // 16B chunk in 512B LDS row
        const int stripe = cx >> 4;            // 0 = even(pr/plane P), 1 = odd
        const int c8 = (cx & 15) * 8;          // ushort offset in stripe
        const bf16x8 w = *(const bf16x8*)&T[row * 256 + cx * 8];
        if (!khalf)
            *(bf16x8*)&qrbuf[(size_t)(m0 + row) * CC + stripe * 512 + (n0 >> 1) + c8] = w;
        else
            *(bf16x8*)&krP[((size_t)(P + stripe * 4) * NN + pos0 + row) * DD + c8] = w;
    }
    #undef SAP
    #undef SBP
}

// ---------------------------------------------------------------------------
// K3: z[m,h] = 1/(dot(qr, R(m)ksum)/N + 1e-6)  (R orthogonal: == q.ksum)
// ---------------------------------------------------------------------------
__global__ __launch_bounds__(256) void z_kernel(
    const unsigned short* __restrict__ qr, const float* __restrict__ ksum,
    float* __restrict__ zbuf)
{
    const int tid = threadIdx.x;
    const int row = tid >> 3;            // 0..31
    const int h = tid & 7;
    const int m = blockIdx.x * 32 + row;
    const int b = m >> 12;
    const int pos = m & (NN - 1);
    const unsigned short* qe = qr + (size_t)m * CC + h * 64;        // pr stripe
    const unsigned short* qo = qe + 512;                            // pi stripe
    const float* km = ksum + b * CC + h * DD;
    float dot = 0.0f;
    #pragma unroll
    for (int j8 = 0; j8 < 8; ++j8) {
        const bf16x8 ev = *(const bf16x8*)&qe[j8 * 8];
        const bf16x8 ov = *(const bf16x8*)&qo[j8 * 8];
        #pragma unroll
        for (int u = 0; u < 8; ++u) {
            const int jj = j8 * 8 + u;
            const int jg = h * 64 + jj;
            const float theta = __builtin_exp2f((float)jg * (-13.287712379549449f / 512.0f));
            float sv, cv;
            __sincosf((float)pos * theta, &sv, &cv);
            const float k0 = km[2 * jj], k1 = km[2 * jj + 1];
            dot = fmaf(bf2f(ev[u]), cv * k0 - sv * k1, dot);
            dot = fmaf(bf2f(ov[u]), cv * k1 + sv * k0, dot);
        }
    }
    dot *= (1.0f / (float)NN);
    zbuf[(size_t)m * HH + h] = 1.0f / (dot + 1e-6f);
}

// ---------------------------------------------------------------------------
// K4: kvpart[slice][bh][d][e] = sum over slice's 256 n of kr[n,d]*v[n,e]
// ---------------------------------------------------------------------------
__global__ __launch_bounds__(256) void kv_kernel(
    const unsigned short* __restrict__ krP, const unsigned short* __restrict__ xpad,
    float* __restrict__ kvpart)
{
    __shared__ float ksm[8][132];
    __shared__ float vsm[8][132];
    const int bh = blockIdx.x;
    const int slice = blockIdx.y;
    const int b = bh >> 3, h = bh & 7;
    const int n0 = slice * 256;
    const int tid = threadIdx.x;
    const int td = (tid >> 4) * 8;
    const int te = (tid & 15) * 8;
    const unsigned short* kp = krP + ((size_t)bh * NN + n0) * DD;
    const unsigned short* vp = xpad + ((size_t)(b * NP) + 1 + n0) * CC + h * DD;
    const int sr = tid >> 5;
    const int sc = (tid & 31) * 4;
    float acc[8][8] = {};
    ushort4 kq = *(const ushort4*)&kp[(size_t)sr * DD + sc];
    ushort4 vq = *(const ushort4*)&vp[(size_t)sr * CC + sc];
    for (int r0 = 0; r0 < 256; r0 += 8) {
        *(float4*)&ksm[sr][sc] = bf4(kq);
        *(float4*)&vsm[sr][sc] = bf4(vq);
        __syncthreads();
        if (r0 + 8 < 256) {
            kq = *(const ushort4*)&kp[(size_t)(r0 + 8 + sr) * DD + sc];
            vq = *(const ushort4*)&vp[(size_t)(r0 + 8 + sr) * CC + sc];
        }
        #pragma unroll
        for (int r = 0; r < 8; ++r) {
            float a[8], bv[8];
            *(float4*)&a[0]  = *(const float4*)&ksm[r][td];
            *(float4*)&a[4]  = *(const float4*)&ksm[r][td + 4];
            *(float4*)&bv[0] = *(const float4*)&vsm[r][te];
            *(float4*)&bv[4] = *(const float4*)&vsm[r][te + 4];
            #pragma unroll
            for (int i = 0; i < 8; ++i)
                #pragma unroll
                for (int j = 0; j < 8; ++j)
                    acc[i][j] = fmaf(a[i], bv[j], acc[i][j]);
        }
        __syncthreads();
    }
    float* op = kvpart + ((size_t)slice * 32 + bh) * (DD * DD);
    #pragma unroll
    for (int i = 0; i < 8; ++i)
        #pragma unroll
        for (int j = 0; j < 8; j += 4)
            *(float4*)&op[(td + i) * DD + te + j] = *(float4*)&acc[i][j];
}

// ---------------------------------------------------------------------------
// K4b: kvT[bh][e][d] = bf16( (1/64) * sum over 16 slices kvpart[sl][bh][d][e] )
// ---------------------------------------------------------------------------
__global__ __launch_bounds__(256) void kv_reduce_t_kernel(
    const float* __restrict__ kvpart, unsigned short* __restrict__ kvT)
{
    __shared__ float t[32][33];
    const int bh = blockIdx.y;
    const int dblk = blockIdx.x >> 2, eblk = blockIdx.x & 3;
    const int tx = threadIdx.x & 31, ty = threadIdx.x >> 5;
    #pragma unroll
    for (int i = 0; i < 4; ++i) {
        const int d = dblk * 32 + ty + i * 8;
        float s = 0.0f;
        #pragma unroll
        for (int sl = 0; sl < 16; ++sl)
            s += kvpart[((size_t)sl * 32 + bh) * (DD * DD) + (size_t)d * DD + eblk * 32 + tx];
        t[ty + i * 8][tx] = s * (1.0f / 64.0f);
    }
    __syncthreads();
    #pragma unroll
    for (int i = 0; i < 4; ++i) {
        const int e = ty + i * 8;
        kvT[((size_t)bh * DD + eblk * 32 + e) * DD + dblk * 32 + tx] = f2bf(t[tx][e]);
    }
}

// ---------------------------------------------------------------------------
// K6 (fused): out = z * (qr @ kv) + conv1d(x, lepe_w, SAME) + lepe_b
// ---------------------------------------------------------------------------
__global__ __launch_bounds__(512) void lepe_mfma(
    const unsigned short* __restrict__ xpad, const unsigned short* __restrict__ wT,
    const float* __restrict__ bias, const unsigned short* __restrict__ qr,
    const unsigned short* __restrict__ kvT, const float* __restrict__ z,
    float* __restrict__ out)
{
    __shared__ __align__(16) unsigned short SA[2][2][8192];
    __shared__ __align__(16) unsigned short SB[2][2][8192];
    const int m0 = blockIdx.x * 256;
    const int n0 = blockIdx.y * 256;
    const int tid = threadIdx.x;
    const int lane = tid & 63;
    const int wv = tid >> 6;
    const int wr = wv >> 2, wc = wv & 3;
    const int b = m0 >> 12;
    const int rbase = m0 + 1 + 2 * b;
    const int rl = lane & 15;
    const int ko0 = (lane >> 4) * 8;
    const int ko1 = 32 + ko0;
    const int blr0 = (wc & 1) * 64;
    const int rb4 = (lane >> 4) * 4;
    const int h0 = n0 >> 7;
    const int hw = h0 + (wc >> 1);

    f32x4 acc[8][4] = {};

    // ---- attn pre-pass: acc = qr(m, head cols) @ kvT^T over K=128 ----
    #pragma unroll
    for (int kt = 0; kt < 2; ++kt) {
        stage_half(&qr[(size_t)m0 * CC + h0 * DD + kt * 64], CC, SA[0][0], tid);
        stage_half(&qr[(size_t)(m0 + 128) * CC + h0 * DD + kt * 64], CC, SA[0][1], tid);
        stage_half(&qr[(size_t)m0 * CC + (h0 + 1) * DD + kt * 64], CC, SA[1][0], tid);
        stage_half(&qr[(size_t)(m0 + 128) * CC + (h0 + 1) * DD + kt * 64], CC, SA[1][1], tid);
        stage_half(&kvT[(size_t)(b * 8 + h0) * DD * DD + kt * 64], DD, SB[0][0], tid);
        stage_half(&kvT[(size_t)(b * 8 + h0) * DD * DD + (size_t)128 * DD + kt * 64], DD, SB[0][1], tid);
        __syncthreads();
        mfma_ktile(SA[wc >> 1][wr], SB[0][wc >> 1], blr0, rl, ko0, acc);
        __syncthreads();
    }

    // ---- scale attn accumulator by z[m, hw] ----
    #pragma unroll
    for (int mf = 0; mf < 8; ++mf)
        #pragma unroll
        for (int r = 0; r < 4; ++r) {
            const float zz = z[(size_t)(m0 + wr * 128 + mf * 16 + rb4 + r) * HH + hw];
            #pragma unroll
            for (int nf = 0; nf < 4; ++nf)
                acc[mf][nf][r] *= zz;
        }
    asm volatile("s_waitcnt vmcnt(0)" ::: "memory");

    // ---- conv main loop (burst-stage 4-phase, NT=48) ----
    const unsigned short* Bgl = &wT[(size_t)n0 * (3 * CC)];
    {
        const unsigned short* A0 = &xpad[(size_t)(rbase - 1) * CC];
        stage_half(A0, CC, SA[0][0], tid);
        stage_half(&A0[(size_t)128 * CC], CC, SA[0][1], tid);
        stage_half(Bgl, 3 * CC, SB[0][0], tid);
        stage_half(&Bgl[(size_t)128 * (3 * CC)], 3 * CC, SB[0][1], tid);
    }
    const int NT = 48;
    for (int t = 0; t < NT; ++t) {
        const int cur = t & 1;
        const int k1 = (t + 1) * 64;
        const int sh1 = (k1 >> 10) - 1;
        const int i1 = k1 & (CC - 1);
        const unsigned short* An = &xpad[(size_t)(rbase + sh1) * CC + i1];
        KTILE_4PHASE(SA[cur][wr], SB[cur][wc >> 1], blr0,
            { stage_half(An, CC, SA[cur ^ 1][0], tid);
              stage_half(&An[(size_t)128 * CC], CC, SA[cur ^ 1][1], tid);
              stage_half(&Bgl[k1], 3 * CC, SB[cur ^ 1][0], tid);
              stage_half(&Bgl[(size_t)128 * (3 * CC) + k1], 3 * CC, SB[cur ^ 1][1], tid); },
            (t + 1 < NT));
    }

    // ---- epilogue: pure write ----
    const int col = lane & 15;
    #pragma unroll
    for (int nf = 0; nf < 4; ++nf) {
        const int n = n0 + wc * 64 + nf * 16 + col;
        const float bn = bias[n];
        #pragma unroll
        for (int mf = 0; mf < 8; ++mf)
            #pragma unroll
            for (int r = 0; r < 4; ++r) {
                const int m = m0 + wr * 128 + mf * 16 + rb4 + r;
                out[(size_t)m * CC + n] = acc[mf][nf][r] + bn;
            }
    }
}

// ---------------------------------------------------------------------------
extern "C" void kernel_launch(void* const* d_in, const int* in_sizes, int n_in,
                              void* d_out, int out_size, void* d_ws, size_t ws_size,
                              hipStream_t stream)
{
    const float* x      = (const float*)d_in[0];
    const float* qk_w   = (const float*)d_in[1];
    const float* qk_b   = (const float*)d_in[2];
    const float* lepe_w = (const float*)d_in[3];
    const float* lepe_b = (const float*)d_in[4];
    float* out = (float*)d_out;

    // fp32 region
    float* ws     = (float*)d_ws;
    float* zbuf   = ws;                                   // MM*HH
    float* ksum   = zbuf + (size_t)MM * HH;               // BB*CC
    float* kvpart = ksum + (size_t)BB * CC;               // 16*32*128*128
    // bf16 region
    unsigned short* xpad  = (unsigned short*)(kvpart + (size_t)16 * 32 * DD * DD);
    unsigned short* wqT   = xpad + (size_t)BB * NP * CC;  // [2048][1024]
    unsigned short* wlT   = wqT + (size_t)2 * CC * CC;    // [1024][3072]
    unsigned short* qrbuf = wlT + (size_t)CC * 3 * CC;    // M*C rope'd q
    unsigned short* krP   = qrbuf + (size_t)MM * CC;      // [32][4096][128]
    unsigned short* kvT   = krP + (size_t)32 * NN * DD;   // [32][128e][128d]

    (void)hipMemsetAsync(ksum, 0, BB * CC * sizeof(float), stream);

    padx_kernel          <<<BB * NP,                      256, 0, stream>>>(x, xpad);
    transpose_bf16_kernel<<<dim3(2 * CC / 32, CC / 32),   256, 0, stream>>>(qk_w, wqT, CC, 2 * CC);
    transpose_bf16_kernel<<<dim3(CC / 32, 3 * CC / 32),   256, 0, stream>>>(lepe_w, wlT, 3 * CC, CC);

    gemm_qk_mfma      <<<dim3(MM / 256, 2048 / 256), 512, 0, stream>>>(xpad, wqT, qk_b, qrbuf, krP, ksum);
    z_kernel          <<<MM / 32,                    256, 0, stream>>>(qrbuf, ksum, zbuf);
    kv_kernel         <<<dim3(32, 16),               256, 0, stream>>>(krP, xpad, kvpart);
    kv_reduce_t_kernel<<<dim3(16, 32),               256, 0, stream>>>(kvpart, kvT);
    lepe_mfma         <<<dim3(MM / 256, CC / 256),   512, 0, stream>>>(xpad, wlT, lepe_b, qrbuf, kvT, zbuf, out);
}